// Round 2
// baseline (4601.615 us; speedup 1.0000x reference)
//
#include <hip/hip_runtime.h>

// Problem constants (from reference)
#define NN 50000
#define EE 1000000
static constexpr float EPSV = 1e-3f;

// ---------------- small elementwise kernels ----------------

__global__ void zero_kernel(float* p, int n) {
    int i = blockIdx.x * blockDim.x + threadIdx.x;
    if (i < n) p[i] = 0.f;
}

__global__ void deg_kernel(const int* __restrict__ ei, const float* __restrict__ ew,
                           float* __restrict__ deg) {
    int e = blockIdx.x * blockDim.x + threadIdx.x;
    if (e < EE) atomicAdd(&deg[ei[EE + e]], ew[e]);
}

__global__ void dinv_kernel(float* deg, int n) {
    int i = blockIdx.x * blockDim.x + threadIdx.x;
    if (i < n) {
        float d = deg[i];
        deg[i] = (d > 0.f) ? rsqrtf(d) : 0.f;
    }
}

__global__ void norm_kernel(const int* __restrict__ ei, const float* __restrict__ ew,
                            const float* __restrict__ dinv, float* __restrict__ nw) {
    int e = blockIdx.x * blockDim.x + threadIdx.x;
    if (e < EE) nw[e] = dinv[ei[e]] * ew[e] * dinv[ei[EE + e]];
}

// ---------------- dual GEMM: Cg = A@Wg ; Cs = A@Ws + bias ----------------
// C tile: 32 rows x (2*Fo) cols. 256 threads: tx=t&31 -> 8 cols, ty=t>>5 -> 4 rows.
// Fo in {128, 40}; both multiples of 8 so a thread's 8 cols live in one matrix.

__global__ __launch_bounds__(256) void gemm_dual(const float* __restrict__ A,
                                                 const float* __restrict__ Wg,
                                                 const float* __restrict__ Ws,
                                                 const float* __restrict__ bias,
                                                 float* __restrict__ Cg, float* __restrict__ Cs,
                                                 int M, int K, int Fo) {
    const int Fo2 = Fo * 2;
    __shared__ float sA[32 * 32];    // 32 rows x 32 k
    __shared__ float sB[32 * 256];   // 32 k x (2*Fo)

    const int t = threadIdx.x;
    const int tx = t & 31, ty = t >> 5;
    const int row0 = blockIdx.x * 32;
    const int c8 = tx * 8;

    float acc[4][8];
#pragma unroll
    for (int r = 0; r < 4; ++r)
#pragma unroll
        for (int c = 0; c < 8; ++c) acc[r][c] = 0.f;

    for (int kc = 0; kc < K; kc += 32) {
        // stage A tile
#pragma unroll
        for (int j = 0; j < 4; ++j) {
            int i = t + j * 256;
            int r = i >> 5, c = i & 31;
            int row = row0 + r;
            float v = 0.f;
            if (row < M) v = A[(size_t)row * K + kc + c];
            sA[i] = v;
        }
        // stage combined B tile [Wg | Ws]
        for (int i = t; i < 32 * Fo2; i += 256) {
            int kk = i / Fo2, c = i - kk * Fo2;
            sB[kk * Fo2 + c] = (c < Fo) ? Wg[(size_t)(kc + kk) * Fo + c]
                                        : Ws[(size_t)(kc + kk) * Fo + (c - Fo)];
        }
        __syncthreads();

        if (c8 < Fo2) {
#pragma unroll 8
            for (int kk = 0; kk < 32; ++kk) {
                float a0 = sA[(ty * 4 + 0) * 32 + kk];
                float a1 = sA[(ty * 4 + 1) * 32 + kk];
                float a2 = sA[(ty * 4 + 2) * 32 + kk];
                float a3 = sA[(ty * 4 + 3) * 32 + kk];
                const float* bp = &sB[kk * Fo2 + c8];
                float4 bv0 = *reinterpret_cast<const float4*>(bp);
                float4 bv1 = *reinterpret_cast<const float4*>(bp + 4);
                float b0 = bv0.x, b1 = bv0.y, b2 = bv0.z, b3 = bv0.w;
                float b4 = bv1.x, b5 = bv1.y, b6 = bv1.z, b7 = bv1.w;
                acc[0][0] += a0 * b0; acc[0][1] += a0 * b1; acc[0][2] += a0 * b2; acc[0][3] += a0 * b3;
                acc[0][4] += a0 * b4; acc[0][5] += a0 * b5; acc[0][6] += a0 * b6; acc[0][7] += a0 * b7;
                acc[1][0] += a1 * b0; acc[1][1] += a1 * b1; acc[1][2] += a1 * b2; acc[1][3] += a1 * b3;
                acc[1][4] += a1 * b4; acc[1][5] += a1 * b5; acc[1][6] += a1 * b6; acc[1][7] += a1 * b7;
                acc[2][0] += a2 * b0; acc[2][1] += a2 * b1; acc[2][2] += a2 * b2; acc[2][3] += a2 * b3;
                acc[2][4] += a2 * b4; acc[2][5] += a2 * b5; acc[2][6] += a2 * b6; acc[2][7] += a2 * b7;
                acc[3][0] += a3 * b0; acc[3][1] += a3 * b1; acc[3][2] += a3 * b2; acc[3][3] += a3 * b3;
                acc[3][4] += a3 * b4; acc[3][5] += a3 * b5; acc[3][6] += a3 * b6; acc[3][7] += a3 * b7;
            }
        }
        __syncthreads();
    }

    if (c8 < Fo2) {
        bool isG = (c8 < Fo);
        int cb = isG ? c8 : c8 - Fo;
        float badd[8];
#pragma unroll
        for (int c = 0; c < 8; ++c) badd[c] = isG ? 0.f : bias[cb + c];
        float* base = isG ? Cg : Cs;
#pragma unroll
        for (int r = 0; r < 4; ++r) {
            int row = row0 + ty * 4 + r;
            if (row < M) {
                float* dst = base + (size_t)row * Fo + cb;
                float4 o0 = make_float4(acc[r][0] + badd[0], acc[r][1] + badd[1],
                                        acc[r][2] + badd[2], acc[r][3] + badd[3]);
                float4 o1 = make_float4(acc[r][4] + badd[4], acc[r][5] + badd[5],
                                        acc[r][6] + badd[6], acc[r][7] + badd[7]);
                *reinterpret_cast<float4*>(dst) = o0;
                *reinterpret_cast<float4*>(dst + 4) = o1;
            }
        }
    }
}

// ---------------- edge scatter: agg[dst] += hw[src] * norm_w ----------------
// CH = Fo/4 feature chunks of float4 per edge.

template <int CH>
__global__ __launch_bounds__(256) void scatter_kernel(const int* __restrict__ ei,
                                                      const float* __restrict__ nw,
                                                      const float* __restrict__ hw,
                                                      float* __restrict__ agg) {
    const int Fo = CH * 4;
    long long idx = (long long)blockIdx.x * 256 + threadIdx.x;
    if (idx >= (long long)EE * CH) return;
    int e = (int)(idx / CH);
    int f = (int)(idx - (long long)e * CH) * 4;
    int s = ei[e], d = ei[EE + e];
    float w = nw[e];
    const float4 hv = *reinterpret_cast<const float4*>(hw + (size_t)s * Fo + f);
    float* ap = agg + (size_t)d * Fo + f;
    atomicAdd(ap + 0, hv.x * w);
    atomicAdd(ap + 1, hv.y * w);
    atomicAdd(ap + 2, hv.z * w);
    atomicAdd(ap + 3, hv.w * w);
}

// ---------------- BatchNorm (+ ReLU) epilogue ----------------

template <bool RELU>
__global__ __launch_bounds__(256) void bn_kernel(const float* __restrict__ in,
                                                 const float* __restrict__ g,
                                                 const float* __restrict__ be,
                                                 const float* __restrict__ mu,
                                                 const float* __restrict__ va,
                                                 float* __restrict__ out, int M, int Fo) {
    int idx = blockIdx.x * 256 + threadIdx.x;
    if (idx >= M * Fo) return;
    int f = idx % Fo;
    float v = in[idx];
    v = (v - mu[f]) * rsqrtf(va[f] + EPSV) * g[f] + be[f];
    if (RELU) v = fmaxf(v, 0.f);
    out[idx] = v;
}

// ---------------- launch ----------------

extern "C" void kernel_launch(void* const* d_in, const int* in_sizes, int n_in,
                              void* d_out, int out_size, void* d_ws, size_t ws_size,
                              hipStream_t stream) {
    const float* x = (const float*)d_in[0];
    const int* ei = (const int*)d_in[1];
    const float* ew = (const float*)d_in[2];

    const float* wg[3]  = {(const float*)d_in[3],  (const float*)d_in[10], (const float*)d_in[17]};
    const float* wsf[3] = {(const float*)d_in[4],  (const float*)d_in[11], (const float*)d_in[18]};
    const float* bs[3]  = {(const float*)d_in[5],  (const float*)d_in[12], (const float*)d_in[19]};
    const float* gm[3]  = {(const float*)d_in[6],  (const float*)d_in[13], (const float*)d_in[20]};
    const float* bt[3]  = {(const float*)d_in[7],  (const float*)d_in[14], (const float*)d_in[21]};
    const float* mu[3]  = {(const float*)d_in[8],  (const float*)d_in[15], (const float*)d_in[22]};
    const float* vr[3]  = {(const float*)d_in[9],  (const float*)d_in[16], (const float*)d_in[23]};

    // workspace layout (floats, 64-float aligned)
    float* W = (float*)d_ws;
    float* deg   = W;                  // NN
    float* normw = W + 50048;          // EE
    float* bufA  = W + 1050048;        // 6.4M  (hw)
    float* bufB  = bufA + 6400000;     // 6.4M  (agg)
    float* bufC  = bufB + 6400000;     // 6.4M  (h intermediate)

    const int B = 256;
    // normalization
    zero_kernel<<<(NN + B - 1) / B, B, 0, stream>>>(deg, NN);
    deg_kernel<<<(EE + B - 1) / B, B, 0, stream>>>(ei, ew, deg);
    dinv_kernel<<<(NN + B - 1) / B, B, 0, stream>>>(deg, NN);
    norm_kernel<<<(EE + B - 1) / B, B, 0, stream>>>(ei, ew, deg, normw);

    const int gemmGrid = (NN + 31) / 32;

    // ---- layer 1: x [N,256] -> 128
    gemm_dual<<<gemmGrid, B, 0, stream>>>(x, wg[0], wsf[0], bs[0], bufA, bufB, NN, 256, 128);
    scatter_kernel<32><<<(int)(((long long)EE * 32 + B - 1) / B), B, 0, stream>>>(ei, normw, bufA, bufB);
    bn_kernel<true><<<(NN * 128 + B - 1) / B, B, 0, stream>>>(bufB, gm[0], bt[0], mu[0], vr[0], bufC, NN, 128);

    // ---- layer 2: h [N,128] -> 128
    gemm_dual<<<gemmGrid, B, 0, stream>>>(bufC, wg[1], wsf[1], bs[1], bufA, bufB, NN, 128, 128);
    scatter_kernel<32><<<(int)(((long long)EE * 32 + B - 1) / B), B, 0, stream>>>(ei, normw, bufA, bufB);
    bn_kernel<true><<<(NN * 128 + B - 1) / B, B, 0, stream>>>(bufB, gm[1], bt[1], mu[1], vr[1], bufC, NN, 128);

    // ---- layer 3: h [N,128] -> 40, output fp32
    gemm_dual<<<gemmGrid, B, 0, stream>>>(bufC, wg[2], wsf[2], bs[2], bufA, bufB, NN, 128, 40);
    scatter_kernel<10><<<(int)(((long long)EE * 10 + B - 1) / B), B, 0, stream>>>(ei, normw, bufA, bufB);
    bn_kernel<false><<<(NN * 40 + B - 1) / B, B, 0, stream>>>(bufB, gm[2], bt[2], mu[2], vr[2], (float*)d_out, NN, 40);
}

// Round 3
// 1035.700 us; speedup vs baseline: 4.4430x; 4.4430x over previous
//
#include <hip/hip_runtime.h>

// Problem constants (from reference)
#define NN 50000
#define EE 1000000
static constexpr float EPSV = 1e-3f;

// ---------------- preprocessing kernels ----------------

__global__ void zero_kernel(float* p, int n) {
    int i = blockIdx.x * blockDim.x + threadIdx.x;
    if (i < n) p[i] = 0.f;
}

// deg[d] += w  AND  cnt[d] += 1 in one pass
__global__ void deg_hist_kernel(const int* __restrict__ ei, const float* __restrict__ ew,
                                float* __restrict__ deg, int* __restrict__ cnt) {
    int e = blockIdx.x * blockDim.x + threadIdx.x;
    if (e < EE) {
        int d = ei[EE + e];
        atomicAdd(&deg[d], ew[e]);
        atomicAdd(&cnt[d], 1);
    }
}

__global__ void dinv_kernel(float* deg, int n) {
    int i = blockIdx.x * blockDim.x + threadIdx.x;
    if (i < n) {
        float d = deg[i];
        deg[i] = (d > 0.f) ? rsqrtf(d) : 0.f;
    }
}

// exclusive scan of cnt[NN] -> rowstart[NN+1], single block of 1024 threads
__global__ __launch_bounds__(1024) void scan_kernel(const int* __restrict__ cnt,
                                                    int* __restrict__ rowstart) {
    __shared__ int sums[1024];
    const int t = threadIdx.x;
    const int CHUNK = (NN + 1023) / 1024;  // 49
    int base = t * CHUNK;
    int s = 0;
    for (int i = 0; i < CHUNK; ++i) {
        int idx = base + i;
        if (idx < NN) s += cnt[idx];
    }
    sums[t] = s;
    __syncthreads();
    for (int off = 1; off < 1024; off <<= 1) {
        int v = (t >= off) ? sums[t - off] : 0;
        __syncthreads();
        sums[t] += v;
        __syncthreads();
    }
    int run = (t == 0) ? 0 : sums[t - 1];  // exclusive prefix for this chunk
    for (int i = 0; i < CHUNK; ++i) {
        int idx = base + i;
        if (idx < NN) {
            rowstart[idx] = run;
            run += cnt[idx];
        }
    }
    if (t == 1023) rowstart[NN] = run;  // == EE
}

// scatter edges into dst-sorted arrays; compute normalized weight inline
__global__ void fill_kernel(const int* __restrict__ ei, const float* __restrict__ ew,
                            const float* __restrict__ dinv, const int* __restrict__ rowstart,
                            int* __restrict__ cnt2, int* __restrict__ esrc,
                            float* __restrict__ ewv) {
    int e = blockIdx.x * blockDim.x + threadIdx.x;
    if (e >= EE) return;
    int s = ei[e], d = ei[EE + e];
    int idx = rowstart[d] + atomicAdd(&cnt2[d], 1);
    esrc[idx] = s;
    ewv[idx] = dinv[s] * ew[e] * dinv[d];
}

// ---------------- dual GEMM: Cg = A@Wg ; Cs = A@Ws + bias ----------------
// NOTE: A and Cs may alias (in-place, row-block aligned): no __restrict__ on them.

__global__ __launch_bounds__(256) void gemm_dual(const float* A,
                                                 const float* __restrict__ Wg,
                                                 const float* __restrict__ Ws,
                                                 const float* __restrict__ bias,
                                                 float* __restrict__ Cg, float* Cs,
                                                 int M, int K, int Fo) {
    const int Fo2 = Fo * 2;
    __shared__ float sA[32 * 32];   // 32 rows x 32 k
    __shared__ float sB[32 * 256];  // 32 k x (2*Fo)

    const int t = threadIdx.x;
    const int tx = t & 31, ty = t >> 5;
    const int row0 = blockIdx.x * 32;
    const int c8 = tx * 8;

    float acc[4][8];
#pragma unroll
    for (int r = 0; r < 4; ++r)
#pragma unroll
        for (int c = 0; c < 8; ++c) acc[r][c] = 0.f;

    for (int kc = 0; kc < K; kc += 32) {
#pragma unroll
        for (int j = 0; j < 4; ++j) {
            int i = t + j * 256;
            int r = i >> 5, c = i & 31;
            int row = row0 + r;
            float v = 0.f;
            if (row < M) v = A[(size_t)row * K + kc + c];
            sA[i] = v;
        }
        for (int i = t; i < 32 * Fo2; i += 256) {
            int kk = i / Fo2, c = i - kk * Fo2;
            sB[kk * Fo2 + c] = (c < Fo) ? Wg[(size_t)(kc + kk) * Fo + c]
                                        : Ws[(size_t)(kc + kk) * Fo + (c - Fo)];
        }
        __syncthreads();

        if (c8 < Fo2) {
#pragma unroll 8
            for (int kk = 0; kk < 32; ++kk) {
                float a0 = sA[(ty * 4 + 0) * 32 + kk];
                float a1 = sA[(ty * 4 + 1) * 32 + kk];
                float a2 = sA[(ty * 4 + 2) * 32 + kk];
                float a3 = sA[(ty * 4 + 3) * 32 + kk];
                const float* bp = &sB[kk * Fo2 + c8];
                float4 bv0 = *reinterpret_cast<const float4*>(bp);
                float4 bv1 = *reinterpret_cast<const float4*>(bp + 4);
                float b0 = bv0.x, b1 = bv0.y, b2 = bv0.z, b3 = bv0.w;
                float b4 = bv1.x, b5 = bv1.y, b6 = bv1.z, b7 = bv1.w;
                acc[0][0] += a0 * b0; acc[0][1] += a0 * b1; acc[0][2] += a0 * b2; acc[0][3] += a0 * b3;
                acc[0][4] += a0 * b4; acc[0][5] += a0 * b5; acc[0][6] += a0 * b6; acc[0][7] += a0 * b7;
                acc[1][0] += a1 * b0; acc[1][1] += a1 * b1; acc[1][2] += a1 * b2; acc[1][3] += a1 * b3;
                acc[1][4] += a1 * b4; acc[1][5] += a1 * b5; acc[1][6] += a1 * b6; acc[1][7] += a1 * b7;
                acc[2][0] += a2 * b0; acc[2][1] += a2 * b1; acc[2][2] += a2 * b2; acc[2][3] += a2 * b3;
                acc[2][4] += a2 * b4; acc[2][5] += a2 * b5; acc[2][6] += a2 * b6; acc[2][7] += a2 * b7;
                acc[3][0] += a3 * b0; acc[3][1] += a3 * b1; acc[3][2] += a3 * b2; acc[3][3] += a3 * b3;
                acc[3][4] += a3 * b4; acc[3][5] += a3 * b5; acc[3][6] += a3 * b6; acc[3][7] += a3 * b7;
            }
        }
        __syncthreads();
    }

    if (c8 < Fo2) {
        bool isG = (c8 < Fo);
        int cb = isG ? c8 : c8 - Fo;
        float badd[8];
#pragma unroll
        for (int c = 0; c < 8; ++c) badd[c] = isG ? 0.f : bias[cb + c];
        float* base = isG ? Cg : Cs;
#pragma unroll
        for (int r = 0; r < 4; ++r) {
            int row = row0 + ty * 4 + r;
            if (row < M) {
                float* dst = base + (size_t)row * Fo + cb;
                float4 o0 = make_float4(acc[r][0] + badd[0], acc[r][1] + badd[1],
                                        acc[r][2] + badd[2], acc[r][3] + badd[3]);
                float4 o1 = make_float4(acc[r][4] + badd[4], acc[r][5] + badd[5],
                                        acc[r][6] + badd[6], acc[r][7] + badd[7]);
                *reinterpret_cast<float4*>(dst) = o0;
                *reinterpret_cast<float4*>(dst + 4) = o1;
            }
        }
    }
}

// ---------------- pull aggregation + fused BN(+ReLU), Fo = 128 ----------------
// one wave per dst node; lane l handles features l and l+64. out may equal selfC
// (each wave reads/writes only its own row).

template <bool RELU>
__global__ __launch_bounds__(256) void agg128_kernel(
    const int* __restrict__ rowstart, const int* __restrict__ esrc,
    const float* __restrict__ ewv, const float* __restrict__ hw,
    const float* selfC, const float* __restrict__ g, const float* __restrict__ be,
    const float* __restrict__ mu, const float* __restrict__ va, float* out) {
    int wave = threadIdx.x >> 6;
    int lane = threadIdx.x & 63;
    int n = blockIdx.x * 4 + wave;
    if (n >= NN) return;
    int beg = rowstart[n], end = rowstart[n + 1];
    float acc0 = selfC[(size_t)n * 128 + lane];
    float acc1 = selfC[(size_t)n * 128 + 64 + lane];
    for (int i = beg; i < end; ++i) {
        int s = esrc[i];
        float w = ewv[i];
        const float* hp = hw + (size_t)s * 128;
        acc0 += hp[lane] * w;
        acc1 += hp[64 + lane] * w;
    }
    float r0 = (acc0 - mu[lane]) * rsqrtf(va[lane] + EPSV) * g[lane] + be[lane];
    float r1 = (acc1 - mu[64 + lane]) * rsqrtf(va[64 + lane] + EPSV) * g[64 + lane] + be[64 + lane];
    if (RELU) {
        r0 = fmaxf(r0, 0.f);
        r1 = fmaxf(r1, 0.f);
    }
    out[(size_t)n * 128 + lane] = r0;
    out[(size_t)n * 128 + 64 + lane] = r1;
}

// ---------------- pull aggregation + fused BN, Fo = 40 (final layer) ----------------

template <bool RELU>
__global__ __launch_bounds__(256) void agg40_kernel(
    const int* __restrict__ rowstart, const int* __restrict__ esrc,
    const float* __restrict__ ewv, const float* __restrict__ hw,
    const float* __restrict__ selfC, const float* __restrict__ g,
    const float* __restrict__ be, const float* __restrict__ mu,
    const float* __restrict__ va, float* __restrict__ out) {
    int wave = threadIdx.x >> 6;
    int lane = threadIdx.x & 63;
    int n = blockIdx.x * 4 + wave;
    if (n >= NN || lane >= 40) return;
    int beg = rowstart[n], end = rowstart[n + 1];
    float acc = selfC[(size_t)n * 40 + lane];
    for (int i = beg; i < end; ++i) {
        int s = esrc[i];
        float w = ewv[i];
        acc += hw[(size_t)s * 40 + lane] * w;
    }
    float r = (acc - mu[lane]) * rsqrtf(va[lane] + EPSV) * g[lane] + be[lane];
    if (RELU) r = fmaxf(r, 0.f);
    out[(size_t)n * 40 + lane] = r;
}

// ---------------- launch ----------------

extern "C" void kernel_launch(void* const* d_in, const int* in_sizes, int n_in,
                              void* d_out, int out_size, void* d_ws, size_t ws_size,
                              hipStream_t stream) {
    const float* x = (const float*)d_in[0];
    const int* ei = (const int*)d_in[1];
    const float* ew = (const float*)d_in[2];

    const float* wg[3]  = {(const float*)d_in[3],  (const float*)d_in[10], (const float*)d_in[17]};
    const float* wsf[3] = {(const float*)d_in[4],  (const float*)d_in[11], (const float*)d_in[18]};
    const float* bs[3]  = {(const float*)d_in[5],  (const float*)d_in[12], (const float*)d_in[19]};
    const float* gm[3]  = {(const float*)d_in[6],  (const float*)d_in[13], (const float*)d_in[20]};
    const float* bt[3]  = {(const float*)d_in[7],  (const float*)d_in[14], (const float*)d_in[21]};
    const float* mu[3]  = {(const float*)d_in[8],  (const float*)d_in[15], (const float*)d_in[22]};
    const float* vr[3]  = {(const float*)d_in[9],  (const float*)d_in[16], (const float*)d_in[23]};

    // workspace layout (floats)
    float* W = (float*)d_ws;
    float* deg      = W;                        // NN (pad to 50048); doubles as dinv
    int*   cnt      = (int*)(W + 50048);        // NN
    int*   cnt2     = (int*)(W + 100096);       // NN
    int*   rowstart = (int*)(W + 150144);       // NN+1 (pad to 50112)
    int*   esrc     = (int*)(W + 200256);       // EE
    float* ewv      = W + 1200256;              // EE
    float* bufA     = W + 2200256;              // 6.4M (hw)
    float* bufC     = bufA + 6400000;           // 6.4M (h / self-term)
    float* selfC3   = bufC + 6400000;           // 2M   (layer-3 self-term)
    // total 17,000,256 floats = 68 MB

    const int B = 256;

    // ---- preprocessing: degree norm + dst-sorted CSR
    zero_kernel<<<(150144 + B - 1) / B, B, 0, stream>>>(W, 150144);  // deg, cnt, cnt2
    deg_hist_kernel<<<(EE + B - 1) / B, B, 0, stream>>>(ei, ew, deg, cnt);
    dinv_kernel<<<(NN + B - 1) / B, B, 0, stream>>>(deg, NN);
    scan_kernel<<<1, 1024, 0, stream>>>(cnt, rowstart);
    fill_kernel<<<(EE + B - 1) / B, B, 0, stream>>>(ei, ew, deg, rowstart, cnt2, esrc, ewv);

    const int gemmGrid = (NN + 31) / 32;
    const int aggGrid = (NN + 3) / 4;

    // ---- layer 1: x [N,256] -> 128
    gemm_dual<<<gemmGrid, B, 0, stream>>>(x, wg[0], wsf[0], bs[0], bufA, bufC, NN, 256, 128);
    agg128_kernel<true><<<aggGrid, B, 0, stream>>>(rowstart, esrc, ewv, bufA, bufC,
                                                   gm[0], bt[0], mu[0], vr[0], bufC);

    // ---- layer 2: h [N,128] -> 128 (Cs in place into bufC: row-block aligned, safe)
    gemm_dual<<<gemmGrid, B, 0, stream>>>(bufC, wg[1], wsf[1], bs[1], bufA, bufC, NN, 128, 128);
    agg128_kernel<true><<<aggGrid, B, 0, stream>>>(rowstart, esrc, ewv, bufA, bufC,
                                                   gm[1], bt[1], mu[1], vr[1], bufC);

    // ---- layer 3: h [N,128] -> 40, output fp32
    gemm_dual<<<gemmGrid, B, 0, stream>>>(bufC, wg[2], wsf[2], bs[2], bufA, selfC3, NN, 128, 40);
    agg40_kernel<false><<<aggGrid, B, 0, stream>>>(rowstart, esrc, ewv, bufA, selfC3,
                                                   gm[2], bt[2], mu[2], vr[2], (float*)d_out);
}

// Round 5
// 762.830 us; speedup vs baseline: 6.0323x; 1.3577x over previous
//
#include <hip/hip_runtime.h>
#include <hip/hip_bf16.h>

#define NN 50000
#define EE 1000000
static constexpr float EPSV = 1e-3f;

typedef __attribute__((ext_vector_type(8))) short short8;
typedef __attribute__((ext_vector_type(4))) float fx4;

__device__ inline float blo(unsigned u) { return __uint_as_float(u << 16); }
__device__ inline float bhi(unsigned u) { return __uint_as_float(u & 0xffff0000u); }
__device__ inline unsigned short f2b(float f) {
    __hip_bfloat16 h = __float2bfloat16(f);
    return *(unsigned short*)&h;
}
__device__ inline unsigned pack2(float a, float b) {
    return (unsigned)f2b(a) | ((unsigned)f2b(b) << 16);
}

// ---------------- preprocessing kernels ----------------

__global__ void zero_kernel(float* p, int n) {
    int i = blockIdx.x * blockDim.x + threadIdx.x;
    if (i < n) p[i] = 0.f;
}

__global__ void deg_hist_kernel(const int* __restrict__ ei, const float* __restrict__ ew,
                                float* __restrict__ deg, int* __restrict__ cnt) {
    int e = blockIdx.x * blockDim.x + threadIdx.x;
    if (e < EE) {
        int d = ei[EE + e];
        atomicAdd(&deg[d], ew[e]);
        atomicAdd(&cnt[d], 1);
    }
}

__global__ void dinv_kernel(float* deg, int n) {
    int i = blockIdx.x * blockDim.x + threadIdx.x;
    if (i < n) {
        float d = deg[i];
        deg[i] = (d > 0.f) ? rsqrtf(d) : 0.f;
    }
}

__global__ __launch_bounds__(1024) void scan_kernel(const int* __restrict__ cnt,
                                                    int* __restrict__ rowstart) {
    __shared__ int sums[1024];
    const int t = threadIdx.x;
    const int CHUNK = (NN + 1023) / 1024;  // 49
    int base = t * CHUNK;
    int s = 0;
    for (int i = 0; i < CHUNK; ++i) {
        int idx = base + i;
        if (idx < NN) s += cnt[idx];
    }
    sums[t] = s;
    __syncthreads();
    for (int off = 1; off < 1024; off <<= 1) {
        int v = (t >= off) ? sums[t - off] : 0;
        __syncthreads();
        sums[t] += v;
        __syncthreads();
    }
    int run = (t == 0) ? 0 : sums[t - 1];
    for (int i = 0; i < CHUNK; ++i) {
        int idx = base + i;
        if (idx < NN) {
            rowstart[idx] = run;
            run += cnt[idx];
        }
    }
    if (t == 1023) rowstart[NN] = run;
}

__global__ void fill_kernel(const int* __restrict__ ei, const float* __restrict__ ew,
                            const float* __restrict__ dinv, const int* __restrict__ rowstart,
                            int* __restrict__ cnt2, int* __restrict__ esrc,
                            float* __restrict__ ewv) {
    int e = blockIdx.x * blockDim.x + threadIdx.x;
    if (e >= EE) return;
    int s = ei[e], d = ei[EE + e];
    int idx = rowstart[d] + atomicAdd(&cnt2[d], 1);
    esrc[idx] = s;
    ewv[idx] = dinv[s] * ew[e] * dinv[d];
}

// ---------------- weight convert: Wt[n][k] bf16, combined [Wg | Ws], padded rows = 0

__global__ void wconv_kernel(const float* __restrict__ Wg, const float* __restrict__ Ws,
                             unsigned short* __restrict__ Wt, int K, int Fo, int N2) {
    int idx = blockIdx.x * 256 + threadIdx.x;
    if (idx >= N2 * K) return;
    int n = idx / K, k = idx - n * K;
    float v = 0.f;
    if (n < Fo) v = Wg[(size_t)k * Fo + n];
    else if (n < 2 * Fo) v = Ws[(size_t)k * Fo + (n - Fo)];
    Wt[idx] = f2b(v);
}

// ---------------- MFMA dual GEMM ----------------
// Block tile 128 rows x 128 cols, 4 waves in 2x2. Wave tile 64x64 = 4x4 of
// 16x16x32 bf16 MFMA. LDS rows padded to 72 bf16 (2-way conflicts only = free).
// Output: cols [0,Fo) -> Cg (bf16), cols [Fo,2Fo) -> Cs (fp32, +bias); cols >= 2Fo dropped.

__device__ inline uint2 load4bf(const float* p) {
    float4 v = *reinterpret_cast<const float4*>(p);
    uint2 r;
    r.x = pack2(v.x, v.y);
    r.y = pack2(v.z, v.w);
    return r;
}
__device__ inline uint2 load4bf(const unsigned short* p) {
    return *reinterpret_cast<const uint2*>(p);
}

template <typename TA>
__global__ __launch_bounds__(256) void gemm_mfma(const TA* __restrict__ A,
                                                 const unsigned short* __restrict__ Wt,
                                                 const float* __restrict__ bias,
                                                 unsigned short* __restrict__ Cg,
                                                 float* __restrict__ Cs,
                                                 int M, int K, int Fo) {
    __shared__ unsigned short sA[128 * 72];
    __shared__ unsigned short sB[128 * 72];

    const int t = threadIdx.x;
    const int lane = t & 63;
    const int wave = t >> 6;
    const int wm = wave >> 1, wn = wave & 1;
    const int l15 = lane & 15, quad = lane >> 4;
    const int row0 = blockIdx.x * 128;
    const int colbase = blockIdx.y * 128;

    fx4 acc[4][4];
#pragma unroll
    for (int r = 0; r < 4; ++r)
#pragma unroll
        for (int c = 0; c < 4; ++c) acc[r][c] = (fx4){0.f, 0.f, 0.f, 0.f};

    for (int kc = 0; kc < K; kc += 64) {
        // stage A: 128 rows x 64 k (convert to bf16 if needed)
#pragma unroll
        for (int j = 0; j < 8; ++j) {
            int i = t + j * 256;
            int row = i >> 4, c4 = (i & 15) * 4;
            int grow = row0 + row;
            uint2 v = make_uint2(0u, 0u);
            if (grow < M) v = load4bf(A + (size_t)grow * K + kc + c4);
            *reinterpret_cast<uint2*>(&sA[row * 72 + c4]) = v;
        }
        // stage B: 128 n-rows x 64 k from Wt (always in-range; pad rows pre-zeroed)
#pragma unroll
        for (int j = 0; j < 8; ++j) {
            int i = t + j * 256;
            int row = i >> 4, c4 = (i & 15) * 4;
            uint2 v = *reinterpret_cast<const uint2*>(Wt + (size_t)(colbase + row) * K + kc + c4);
            *reinterpret_cast<uint2*>(&sB[row * 72 + c4]) = v;
        }
        __syncthreads();

#pragma unroll
        for (int kh = 0; kh < 2; ++kh) {
            short8 a[4], b[4];
#pragma unroll
            for (int r = 0; r < 4; ++r)
                a[r] = *reinterpret_cast<const short8*>(&sA[(wm * 64 + r * 16 + l15) * 72 + kh * 32 + quad * 8]);
#pragma unroll
            for (int c = 0; c < 4; ++c)
                b[c] = *reinterpret_cast<const short8*>(&sB[(wn * 64 + c * 16 + l15) * 72 + kh * 32 + quad * 8]);
#pragma unroll
            for (int r = 0; r < 4; ++r)
#pragma unroll
                for (int c = 0; c < 4; ++c)
                    acc[r][c] = __builtin_amdgcn_mfma_f32_16x16x32_bf16(a[r], b[c], acc[r][c], 0, 0, 0);
        }
        __syncthreads();
    }

    // epilogue (C/D layout: col = lane&15, row = quad*4 + reg)
#pragma unroll
    for (int c = 0; c < 4; ++c) {
        int f = colbase + wn * 64 + c * 16 + l15;
        if (f >= 2 * Fo) continue;
        bool isG = (f < Fo);
        int col = isG ? f : f - Fo;
        float badd = isG ? 0.f : bias[col];
#pragma unroll
        for (int r = 0; r < 4; ++r) {
#pragma unroll
            for (int reg = 0; reg < 4; ++reg) {
                int row = row0 + wm * 64 + r * 16 + quad * 4 + reg;
                if (row < M) {
                    float v = acc[r][c][reg] + badd;
                    if (isG)
                        Cg[(size_t)row * Fo + col] = f2b(v);
                    else
                        Cs[(size_t)row * Fo + col] = v;
                }
            }
        }
    }
}

// ---------------- pull aggregation + fused BN/ReLU, Fo=128, bf16 in, bf16 out
// 128 bf16 per row = 64 unsigned; lane handles features 2*lane, 2*lane+1.

template <bool RELU>
__global__ __launch_bounds__(256) void agg128_kernel(
    const int* __restrict__ rowstart, const int* __restrict__ esrc,
    const float* __restrict__ ewv, const unsigned* __restrict__ hw,
    const float* __restrict__ selfC, const float* __restrict__ g,
    const float* __restrict__ be, const float* __restrict__ mu,
    const float* __restrict__ va, unsigned* __restrict__ out) {
    int wave = threadIdx.x >> 6;
    int lane = threadIdx.x & 63;
    int n = blockIdx.x * 4 + wave;
    if (n >= NN) return;
    int f0 = lane * 2, f1 = f0 + 1;
    float acc0 = selfC[(size_t)n * 128 + f0];
    float acc1 = selfC[(size_t)n * 128 + f1];
    int beg = rowstart[n], end = rowstart[n + 1];
    for (int i = beg; i < end; ++i) {
        int s = esrc[i];
        float w = ewv[i];
        unsigned v = hw[(size_t)s * 64 + lane];
        acc0 += blo(v) * w;
        acc1 += bhi(v) * w;
    }
    float r0 = (acc0 - mu[f0]) * rsqrtf(va[f0] + EPSV) * g[f0] + be[f0];
    float r1 = (acc1 - mu[f1]) * rsqrtf(va[f1] + EPSV) * g[f1] + be[f1];
    if (RELU) {
        r0 = fmaxf(r0, 0.f);
        r1 = fmaxf(r1, 0.f);
    }
    out[(size_t)n * 64 + lane] = pack2(r0, r1);
}

// ---------------- final layer aggregation, Fo=40 (20 unsigned/row), bf16 in, fp32 out

__global__ __launch_bounds__(256) void agg40_kernel(
    const int* __restrict__ rowstart, const int* __restrict__ esrc,
    const float* __restrict__ ewv, const unsigned* __restrict__ hw,
    const float* __restrict__ selfC, const float* __restrict__ g,
    const float* __restrict__ be, const float* __restrict__ mu,
    const float* __restrict__ va, float* __restrict__ out) {
    int wave = threadIdx.x >> 6;
    int lane = threadIdx.x & 63;
    int n = blockIdx.x * 4 + wave;
    if (n >= NN || lane >= 20) return;
    int f0 = lane * 2, f1 = f0 + 1;
    float acc0 = selfC[(size_t)n * 40 + f0];
    float acc1 = selfC[(size_t)n * 40 + f1];
    int beg = rowstart[n], end = rowstart[n + 1];
    for (int i = beg; i < end; ++i) {
        int s = esrc[i];
        float w = ewv[i];
        unsigned v = hw[(size_t)s * 20 + lane];
        acc0 += blo(v) * w;
        acc1 += bhi(v) * w;
    }
    float r0 = (acc0 - mu[f0]) * rsqrtf(va[f0] + EPSV) * g[f0] + be[f0];
    float r1 = (acc1 - mu[f1]) * rsqrtf(va[f1] + EPSV) * g[f1] + be[f1];
    float2 o = make_float2(r0, r1);
    *reinterpret_cast<float2*>(&out[(size_t)n * 40 + f0]) = o;
}

// ---------------- launch ----------------

extern "C" void kernel_launch(void* const* d_in, const int* in_sizes, int n_in,
                              void* d_out, int out_size, void* d_ws, size_t ws_size,
                              hipStream_t stream) {
    const float* x = (const float*)d_in[0];
    const int* ei = (const int*)d_in[1];
    const float* ew = (const float*)d_in[2];

    const float* wg[3]  = {(const float*)d_in[3],  (const float*)d_in[10], (const float*)d_in[17]};
    const float* wsf[3] = {(const float*)d_in[4],  (const float*)d_in[11], (const float*)d_in[18]};
    const float* bs[3]  = {(const float*)d_in[5],  (const float*)d_in[12], (const float*)d_in[19]};
    const float* gm[3]  = {(const float*)d_in[6],  (const float*)d_in[13], (const float*)d_in[20]};
    const float* bt[3]  = {(const float*)d_in[7],  (const float*)d_in[14], (const float*)d_in[21]};
    const float* mu[3]  = {(const float*)d_in[8],  (const float*)d_in[15], (const float*)d_in[22]};
    const float* vr[3]  = {(const float*)d_in[9],  (const float*)d_in[16], (const float*)d_in[23]};

    // workspace layout (float-sized slots)
    float* W = (float*)d_ws;
    float* deg      = W;                         // 50048
    int*   cnt      = (int*)(W + 50048);         // 50048
    int*   cnt2     = (int*)(W + 100096);        // 50048
    int*   rowstart = (int*)(W + 150144);        // 50112
    int*   esrc     = (int*)(W + 200256);        // 1,000,000
    float* ewv      = W + 1200256;               // 1,000,000
    unsigned short* Wt1 = (unsigned short*)(W + 2200256);  // 256*256 bf16 (32768 slots)
    unsigned short* Wt2 = (unsigned short*)(W + 2233024);  // 256*128 bf16 (16384 slots)
    unsigned short* Wt3 = (unsigned short*)(W + 2249408);  // 128*128 bf16 (8192 slots)
    unsigned short* bufHW = (unsigned short*)(W + 2257600);  // 50000*128 bf16 (3.2M slots); also hw3 [M][40]
    float* bufS     = W + 5457600;               // 50000*128 fp32 (6.4M); also selfC3 [M][40]
    unsigned short* bufH = (unsigned short*)(W + 11857600);  // 50000*128 bf16 (3.2M slots)
    // end ~= 15,057,600 floats = 60.2 MB

    const int B = 256;

    // preprocessing: degree norm + dst-sorted CSR
    zero_kernel<<<(150144 + B - 1) / B, B, 0, stream>>>(W, 150144);
    deg_hist_kernel<<<(EE + B - 1) / B, B, 0, stream>>>(ei, ew, deg, cnt);
    dinv_kernel<<<(NN + B - 1) / B, B, 0, stream>>>(deg, NN);
    scan_kernel<<<1, 1024, 0, stream>>>(cnt, rowstart);
    fill_kernel<<<(EE + B - 1) / B, B, 0, stream>>>(ei, ew, deg, rowstart, cnt2, esrc, ewv);

    // weight conversion
    wconv_kernel<<<(256 * 256 + B - 1) / B, B, 0, stream>>>(wg[0], wsf[0], Wt1, 256, 128, 256);
    wconv_kernel<<<(256 * 128 + B - 1) / B, B, 0, stream>>>(wg[1], wsf[1], Wt2, 128, 128, 256);
    wconv_kernel<<<(128 * 128 + B - 1) / B, B, 0, stream>>>(wg[2], wsf[2], Wt3, 128, 40, 128);

    const int aggGrid = (NN + 3) / 4;
    dim3 g2((NN + 127) / 128, 2), g1((NN + 127) / 128, 1);

    // layer 1: x fp32 [N,256] -> 128
    gemm_mfma<float><<<g2, B, 0, stream>>>(x, Wt1, bs[0], bufHW, bufS, NN, 256, 128);
    agg128_kernel<true><<<aggGrid, B, 0, stream>>>(rowstart, esrc, ewv, (const unsigned*)bufHW,
                                                   bufS, gm[0], bt[0], mu[0], vr[0], (unsigned*)bufH);

    // layer 2: h bf16 [N,128] -> 128
    gemm_mfma<unsigned short><<<g2, B, 0, stream>>>(bufH, Wt2, bs[1], bufHW, bufS, NN, 128, 128);
    agg128_kernel<true><<<aggGrid, B, 0, stream>>>(rowstart, esrc, ewv, (const unsigned*)bufHW,
                                                   bufS, gm[1], bt[1], mu[1], vr[1], (unsigned*)bufH);

    // layer 3: h bf16 [N,128] -> 40 (padded to 128 cols), fp32 out
    gemm_mfma<unsigned short><<<g1, B, 0, stream>>>(bufH, Wt3, bs[2], bufHW, bufS, NN, 128, 40);
    agg40_kernel<<<aggGrid, B, 0, stream>>>(rowstart, esrc, ewv, (const unsigned*)bufHW,
                                            bufS, gm[2], bt[2], mu[2], vr[2], (float*)d_out);
}

// Round 6
// 609.605 us; speedup vs baseline: 7.5485x; 1.2514x over previous
//
#include <hip/hip_runtime.h>
#include <hip/hip_bf16.h>

#define NN 50000
#define EE 1000000
static constexpr float EPSV = 1e-3f;

typedef __attribute__((ext_vector_type(8))) short short8;
typedef __attribute__((ext_vector_type(4))) float fx4;

__device__ inline float blo(unsigned u) { return __uint_as_float(u << 16); }
__device__ inline float bhi(unsigned u) { return __uint_as_float(u & 0xffff0000u); }
__device__ inline unsigned short f2b(float f) {
    __hip_bfloat16 h = __float2bfloat16(f);
    return *(unsigned short*)&h;
}
__device__ inline unsigned pack2(float a, float b) {
    return (unsigned)f2b(a) | ((unsigned)f2b(b) << 16);
}

// ---------------- preprocessing kernels ----------------

__global__ void zero_kernel(float* p, int n) {
    int i = blockIdx.x * blockDim.x + threadIdx.x;
    if (i < n) p[i] = 0.f;
}

__global__ void deg_hist_kernel(const int* __restrict__ ei, const float* __restrict__ ew,
                                float* __restrict__ deg, int* __restrict__ cnt) {
    int e = blockIdx.x * blockDim.x + threadIdx.x;
    if (e < EE) {
        int d = ei[EE + e];
        atomicAdd(&deg[d], ew[e]);
        atomicAdd(&cnt[d], 1);
    }
}

__global__ void dinv_kernel(float* deg, int n) {
    int i = blockIdx.x * blockDim.x + threadIdx.x;
    if (i < n) {
        float d = deg[i];
        deg[i] = (d > 0.f) ? rsqrtf(d) : 0.f;
    }
}

__global__ __launch_bounds__(1024) void scan_kernel(const int* __restrict__ cnt,
                                                    int* __restrict__ rowstart) {
    __shared__ int sums[1024];
    const int t = threadIdx.x;
    const int CHUNK = (NN + 1023) / 1024;  // 49
    int base = t * CHUNK;
    int s = 0;
    for (int i = 0; i < CHUNK; ++i) {
        int idx = base + i;
        if (idx < NN) s += cnt[idx];
    }
    sums[t] = s;
    __syncthreads();
    for (int off = 1; off < 1024; off <<= 1) {
        int v = (t >= off) ? sums[t - off] : 0;
        __syncthreads();
        sums[t] += v;
        __syncthreads();
    }
    int run = (t == 0) ? 0 : sums[t - 1];
    for (int i = 0; i < CHUNK; ++i) {
        int idx = base + i;
        if (idx < NN) {
            rowstart[idx] = run;
            run += cnt[idx];
        }
    }
    if (t == 1023) rowstart[NN] = run;
}

// scatter edges into dst-sorted record array {src, normalized weight} (8 B each)
__global__ void fill_kernel(const int* __restrict__ ei, const float* __restrict__ ew,
                            const float* __restrict__ dinv, const int* __restrict__ rowstart,
                            int* __restrict__ cnt2, uint2* __restrict__ eprec) {
    int e = blockIdx.x * blockDim.x + threadIdx.x;
    if (e >= EE) return;
    int s = ei[e], d = ei[EE + e];
    int idx = rowstart[d] + atomicAdd(&cnt2[d], 1);
    float w = dinv[s] * ew[e] * dinv[d];
    eprec[idx] = make_uint2((unsigned)s, __float_as_uint(w));
}

// ---------------- weight convert: Wt[n][k] bf16, combined [Wg | Ws], padded rows = 0

__global__ void wconv_kernel(const float* __restrict__ Wg, const float* __restrict__ Ws,
                             unsigned short* __restrict__ Wt, int K, int Fo, int N2) {
    int idx = blockIdx.x * 256 + threadIdx.x;
    if (idx >= N2 * K) return;
    int n = idx / K, k = idx - n * K;
    float v = 0.f;
    if (n < Fo) v = Wg[(size_t)k * Fo + n];
    else if (n < 2 * Fo) v = Ws[(size_t)k * Fo + (n - Fo)];
    Wt[idx] = f2b(v);
}

// ---------------- MFMA dual GEMM (unchanged from R5) ----------------

__device__ inline uint2 load4bf(const float* p) {
    float4 v = *reinterpret_cast<const float4*>(p);
    uint2 r;
    r.x = pack2(v.x, v.y);
    r.y = pack2(v.z, v.w);
    return r;
}
__device__ inline uint2 load4bf(const unsigned short* p) {
    return *reinterpret_cast<const uint2*>(p);
}

template <typename TA>
__global__ __launch_bounds__(256) void gemm_mfma(const TA* __restrict__ A,
                                                 const unsigned short* __restrict__ Wt,
                                                 const float* __restrict__ bias,
                                                 unsigned short* __restrict__ Cg,
                                                 float* __restrict__ Cs,
                                                 int M, int K, int Fo) {
    __shared__ unsigned short sA[128 * 72];
    __shared__ unsigned short sB[128 * 72];

    const int t = threadIdx.x;
    const int lane = t & 63;
    const int wave = t >> 6;
    const int wm = wave >> 1, wn = wave & 1;
    const int l15 = lane & 15, quad = lane >> 4;
    const int row0 = blockIdx.x * 128;
    const int colbase = blockIdx.y * 128;

    fx4 acc[4][4];
#pragma unroll
    for (int r = 0; r < 4; ++r)
#pragma unroll
        for (int c = 0; c < 4; ++c) acc[r][c] = (fx4){0.f, 0.f, 0.f, 0.f};

    for (int kc = 0; kc < K; kc += 64) {
#pragma unroll
        for (int j = 0; j < 8; ++j) {
            int i = t + j * 256;
            int row = i >> 4, c4 = (i & 15) * 4;
            int grow = row0 + row;
            uint2 v = make_uint2(0u, 0u);
            if (grow < M) v = load4bf(A + (size_t)grow * K + kc + c4);
            *reinterpret_cast<uint2*>(&sA[row * 72 + c4]) = v;
        }
#pragma unroll
        for (int j = 0; j < 8; ++j) {
            int i = t + j * 256;
            int row = i >> 4, c4 = (i & 15) * 4;
            uint2 v = *reinterpret_cast<const uint2*>(Wt + (size_t)(colbase + row) * K + kc + c4);
            *reinterpret_cast<uint2*>(&sB[row * 72 + c4]) = v;
        }
        __syncthreads();

#pragma unroll
        for (int kh = 0; kh < 2; ++kh) {
            short8 a[4], b[4];
#pragma unroll
            for (int r = 0; r < 4; ++r)
                a[r] = *reinterpret_cast<const short8*>(&sA[(wm * 64 + r * 16 + l15) * 72 + kh * 32 + quad * 8]);
#pragma unroll
            for (int c = 0; c < 4; ++c)
                b[c] = *reinterpret_cast<const short8*>(&sB[(wn * 64 + c * 16 + l15) * 72 + kh * 32 + quad * 8]);
#pragma unroll
            for (int r = 0; r < 4; ++r)
#pragma unroll
                for (int c = 0; c < 4; ++c)
                    acc[r][c] = __builtin_amdgcn_mfma_f32_16x16x32_bf16(a[r], b[c], acc[r][c], 0, 0, 0);
        }
        __syncthreads();
    }

    // epilogue (C/D layout: col = lane&15, row = quad*4 + reg)
#pragma unroll
    for (int c = 0; c < 4; ++c) {
        int f = colbase + wn * 64 + c * 16 + l15;
        if (f >= 2 * Fo) continue;
        bool isG = (f < Fo);
        int col = isG ? f : f - Fo;
        float badd = isG ? 0.f : bias[col];
#pragma unroll
        for (int r = 0; r < 4; ++r) {
#pragma unroll
            for (int reg = 0; reg < 4; ++reg) {
                int row = row0 + wm * 64 + r * 16 + quad * 4 + reg;
                if (row < M) {
                    float v = acc[r][c][reg] + badd;
                    if (isG)
                        Cg[(size_t)row * Fo + col] = f2b(v);
                    else
                        Cs[(size_t)row * Fo + col] = v;
                }
            }
        }
    }
}

// ---------------- pull aggregation + fused BN/ReLU, Fo=128, bf16 in/out
// one wave per node; lane covers features 2*lane, 2*lane+1; 4 edges in flight.

template <bool RELU>
__global__ __launch_bounds__(256) void agg128_kernel(
    const int* __restrict__ rowstart, const uint2* __restrict__ eprec,
    const unsigned* __restrict__ hw, const float* __restrict__ selfC,
    const float* __restrict__ g, const float* __restrict__ be,
    const float* __restrict__ mu, const float* __restrict__ va,
    unsigned* __restrict__ out) {
    int wave = threadIdx.x >> 6;
    int lane = threadIdx.x & 63;
    int n = blockIdx.x * 4 + wave;
    if (n >= NN) return;
    float2 sc = reinterpret_cast<const float2*>(selfC)[n * 64 + lane];
    float acc0 = sc.x, acc1 = sc.y;
    int beg = rowstart[n], end = rowstart[n + 1];
    int i = beg;
    for (; i + 4 <= end; i += 4) {
        uint2 e0 = eprec[i], e1 = eprec[i + 1], e2 = eprec[i + 2], e3 = eprec[i + 3];
        unsigned v0 = hw[e0.x * 64u + lane];
        unsigned v1 = hw[e1.x * 64u + lane];
        unsigned v2 = hw[e2.x * 64u + lane];
        unsigned v3 = hw[e3.x * 64u + lane];
        float w0 = __uint_as_float(e0.y), w1 = __uint_as_float(e1.y);
        float w2 = __uint_as_float(e2.y), w3 = __uint_as_float(e3.y);
        acc0 += blo(v0) * w0; acc1 += bhi(v0) * w0;
        acc0 += blo(v1) * w1; acc1 += bhi(v1) * w1;
        acc0 += blo(v2) * w2; acc1 += bhi(v2) * w2;
        acc0 += blo(v3) * w3; acc1 += bhi(v3) * w3;
    }
    for (; i < end; ++i) {
        uint2 e = eprec[i];
        unsigned v = hw[e.x * 64u + lane];
        float w = __uint_as_float(e.y);
        acc0 += blo(v) * w; acc1 += bhi(v) * w;
    }
    float2 m2 = reinterpret_cast<const float2*>(mu)[lane];
    float2 v2f = reinterpret_cast<const float2*>(va)[lane];
    float2 g2 = reinterpret_cast<const float2*>(g)[lane];
    float2 b2 = reinterpret_cast<const float2*>(be)[lane];
    float r0 = (acc0 - m2.x) * rsqrtf(v2f.x + EPSV) * g2.x + b2.x;
    float r1 = (acc1 - m2.y) * rsqrtf(v2f.y + EPSV) * g2.y + b2.y;
    if (RELU) {
        r0 = fmaxf(r0, 0.f);
        r1 = fmaxf(r1, 0.f);
    }
    out[n * 64 + lane] = pack2(r0, r1);
}

// ---------------- final layer aggregation, Fo=40 (20 dwords/row), fp32 out
// 3 lane-groups of 20 walk every-3rd edge (3 gathers in flight), shfl-combine.

__global__ __launch_bounds__(256) void agg40_kernel(
    const int* __restrict__ rowstart, const uint2* __restrict__ eprec,
    const unsigned* __restrict__ hw, const float* __restrict__ selfC,
    const float* __restrict__ g, const float* __restrict__ be,
    const float* __restrict__ mu, const float* __restrict__ va,
    float* __restrict__ out) {
    int wave = threadIdx.x >> 6;
    int lane = threadIdx.x & 63;
    int n = blockIdx.x * 4 + wave;
    if (n >= NN) return;
    int grp = lane / 20;        // 0..3 (grp 3 = lanes 60-63 idle)
    int fl = lane - grp * 20;   // 0..19
    float acc0 = 0.f, acc1 = 0.f;
    int beg = rowstart[n], end = rowstart[n + 1];
    if (grp < 3) {
        for (int i = beg + grp; i < end; i += 3) {
            uint2 e = eprec[i];
            unsigned v = hw[e.x * 20u + fl];
            float w = __uint_as_float(e.y);
            acc0 += blo(v) * w;
            acc1 += bhi(v) * w;
        }
    }
    // combine the 3 group partials into lanes 0..19
    acc0 += __shfl(acc0, lane + 20) + __shfl(acc0, lane + 40);
    acc1 += __shfl(acc1, lane + 20) + __shfl(acc1, lane + 40);
    if (lane < 20) {
        int f0 = lane * 2;
        float2 sc = reinterpret_cast<const float2*>(selfC)[n * 20 + lane];
        acc0 += sc.x;
        acc1 += sc.y;
        float2 m2 = reinterpret_cast<const float2*>(mu)[lane];
        float2 v2f = reinterpret_cast<const float2*>(va)[lane];
        float2 g2 = reinterpret_cast<const float2*>(g)[lane];
        float2 b2 = reinterpret_cast<const float2*>(be)[lane];
        float r0 = (acc0 - m2.x) * rsqrtf(v2f.x + EPSV) * g2.x + b2.x;
        float r1 = (acc1 - m2.y) * rsqrtf(v2f.y + EPSV) * g2.y + b2.y;
        *reinterpret_cast<float2*>(&out[(size_t)n * 40 + f0]) = make_float2(r0, r1);
    }
}

// ---------------- launch ----------------

extern "C" void kernel_launch(void* const* d_in, const int* in_sizes, int n_in,
                              void* d_out, int out_size, void* d_ws, size_t ws_size,
                              hipStream_t stream) {
    const float* x = (const float*)d_in[0];
    const int* ei = (const int*)d_in[1];
    const float* ew = (const float*)d_in[2];

    const float* wg[3]  = {(const float*)d_in[3],  (const float*)d_in[10], (const float*)d_in[17]};
    const float* wsf[3] = {(const float*)d_in[4],  (const float*)d_in[11], (const float*)d_in[18]};
    const float* bs[3]  = {(const float*)d_in[5],  (const float*)d_in[12], (const float*)d_in[19]};
    const float* gm[3]  = {(const float*)d_in[6],  (const float*)d_in[13], (const float*)d_in[20]};
    const float* bt[3]  = {(const float*)d_in[7],  (const float*)d_in[14], (const float*)d_in[21]};
    const float* mu[3]  = {(const float*)d_in[8],  (const float*)d_in[15], (const float*)d_in[22]};
    const float* vr[3]  = {(const float*)d_in[9],  (const float*)d_in[16], (const float*)d_in[23]};

    // workspace layout (float-sized slots)
    float* W = (float*)d_ws;
    float* deg      = W;                         // 50048
    int*   cnt      = (int*)(W + 50048);         // 50048
    int*   cnt2     = (int*)(W + 100096);        // 50048
    int*   rowstart = (int*)(W + 150144);        // 50112
    uint2* eprec    = (uint2*)(W + 200256);      // 1,000,000 records (2M slots)
    unsigned short* Wt1 = (unsigned short*)(W + 2200256);  // 256*256 bf16
    unsigned short* Wt2 = (unsigned short*)(W + 2233024);  // 256*128 bf16
    unsigned short* Wt3 = (unsigned short*)(W + 2249408);  // 128*128 bf16
    unsigned short* bufHW = (unsigned short*)(W + 2257600);  // 50000*128 bf16; also hw3 [M][40]
    float* bufS     = W + 5457600;               // 50000*128 fp32; also selfC3 [M][40]
    unsigned short* bufH = (unsigned short*)(W + 11857600);  // 50000*128 bf16

    const int B = 256;

    // preprocessing: degree norm + dst-sorted CSR
    zero_kernel<<<(150144 + B - 1) / B, B, 0, stream>>>(W, 150144);
    deg_hist_kernel<<<(EE + B - 1) / B, B, 0, stream>>>(ei, ew, deg, cnt);
    dinv_kernel<<<(NN + B - 1) / B, B, 0, stream>>>(deg, NN);
    scan_kernel<<<1, 1024, 0, stream>>>(cnt, rowstart);
    fill_kernel<<<(EE + B - 1) / B, B, 0, stream>>>(ei, ew, deg, rowstart, cnt2, eprec);

    // weight conversion
    wconv_kernel<<<(256 * 256 + B - 1) / B, B, 0, stream>>>(wg[0], wsf[0], Wt1, 256, 128, 256);
    wconv_kernel<<<(256 * 128 + B - 1) / B, B, 0, stream>>>(wg[1], wsf[1], Wt2, 128, 128, 256);
    wconv_kernel<<<(128 * 128 + B - 1) / B, B, 0, stream>>>(wg[2], wsf[2], Wt3, 128, 40, 128);

    const int aggGrid = (NN + 3) / 4;
    dim3 g2((NN + 127) / 128, 2), g1((NN + 127) / 128, 1);

    // layer 1: x fp32 [N,256] -> 128
    gemm_mfma<float><<<g2, B, 0, stream>>>(x, Wt1, bs[0], bufHW, bufS, NN, 256, 128);
    agg128_kernel<true><<<aggGrid, B, 0, stream>>>(rowstart, eprec, (const unsigned*)bufHW,
                                                   bufS, gm[0], bt[0], mu[0], vr[0], (unsigned*)bufH);

    // layer 2: h bf16 [N,128] -> 128
    gemm_mfma<unsigned short><<<g2, B, 0, stream>>>(bufH, Wt2, bs[1], bufHW, bufS, NN, 128, 128);
    agg128_kernel<true><<<aggGrid, B, 0, stream>>>(rowstart, eprec, (const unsigned*)bufHW,
                                                   bufS, gm[1], bt[1], mu[1], vr[1], (unsigned*)bufH);

    // layer 3: h bf16 [N,128] -> 40 (padded to 128 cols), fp32 out
    gemm_mfma<unsigned short><<<g1, B, 0, stream>>>(bufH, Wt3, bs[2], bufHW, bufS, NN, 128, 40);
    agg40_kernel<<<aggGrid, B, 0, stream>>>(rowstart, eprec, (const unsigned*)bufHW,
                                            bufS, gm[2], bt[2], mu[2], vr[2], (float*)d_out);
}

// Round 7
// 481.690 us; speedup vs baseline: 9.5531x; 1.2656x over previous
//
#include <hip/hip_runtime.h>
#include <hip/hip_bf16.h>

#define NN 50000
#define EE 1000000
static constexpr float EPSV = 1e-3f;
static constexpr float FIXSCALE = 16777216.f;  // 2^24

typedef __attribute__((ext_vector_type(8))) short short8;
typedef __attribute__((ext_vector_type(4))) float fx4;

__device__ inline float blo(unsigned u) { return __uint_as_float(u << 16); }
__device__ inline float bhi(unsigned u) { return __uint_as_float(u & 0xffff0000u); }
__device__ inline unsigned short f2b(float f) {
    __hip_bfloat16 h = __float2bfloat16(f);
    return *(unsigned short*)&h;
}
__device__ inline unsigned pack2(float a, float b) {
    return (unsigned)f2b(a) | ((unsigned)f2b(b) << 16);
}

// ---------------- preprocessing ----------------

__global__ void zero_kernel(float* p, int n) {
    int i = blockIdx.x * blockDim.x + threadIdx.x;
    if (i < n) p[i] = 0.f;
}

// one uint64 atomic per edge: high32 = count, low32 = deg in 8.24 fixed point
// (max degree << 256, so the low word never carries into the count)
__global__ void cntdeg_kernel(const int* __restrict__ ei, const float* __restrict__ ew,
                              unsigned long long* __restrict__ cnt64) {
    int e = blockIdx.x * blockDim.x + threadIdx.x;
    if (e < EE) {
        int d = ei[EE + e];
        unsigned fx = __float2uint_rn(ew[e] * FIXSCALE);
        atomicAdd(&cnt64[d], 0x100000000ull | (unsigned long long)fx);
    }
}

// dinv[i] = deg>0 ? rsqrt(deg) : 0  AND per-block (1024-elem) count sums
__global__ __launch_bounds__(1024) void dinvsum_kernel(const uint2* __restrict__ cnt64,
                                                       float* __restrict__ dinv,
                                                       int* __restrict__ bsum) {
    __shared__ int s[1024];
    const int t = threadIdx.x;
    int idx = blockIdx.x * 1024 + t;
    uint2 cv = make_uint2(0u, 0u);
    if (idx < NN) cv = cnt64[idx];
    float deg = (float)cv.x * (1.f / FIXSCALE);
    if (idx < NN) dinv[idx] = (deg > 0.f) ? rsqrtf(deg) : 0.f;
    s[t] = (int)cv.y;
    __syncthreads();
#pragma unroll
    for (int off = 512; off > 0; off >>= 1) {
        if (t < off) s[t] += s[t + off];
        __syncthreads();
    }
    if (t == 0) bsum[blockIdx.x] = s[0];
}

// exclusive scan of 49 block sums (single wave)
__global__ __launch_bounds__(64) void scanB_kernel(const int* __restrict__ bsum,
                                                   int* __restrict__ bpre, int nb) {
    int t = threadIdx.x;
    int v = (t < nb) ? bsum[t] : 0;
    int own = v;
#pragma unroll
    for (int off = 1; off < 64; off <<= 1) {
        int u = __shfl_up(v, off);
        if (t >= off) v += u;
    }
    if (t < nb) bpre[t] = v - own;
}

// block-local inclusive scan (1024 elems) + block prefix -> exclusive rowstart
__global__ __launch_bounds__(1024) void scanC_kernel(const uint2* __restrict__ cnt64,
                                                     const int* __restrict__ bpre,
                                                     int* __restrict__ rowstart) {
    __shared__ int s[1024];
    const int t = threadIdx.x;
    int idx = blockIdx.x * 1024 + t;
    int v = (idx < NN) ? (int)cnt64[idx].y : 0;
    s[t] = v;
    __syncthreads();
#pragma unroll
    for (int off = 1; off < 1024; off <<= 1) {
        int u = (t >= off) ? s[t - off] : 0;
        __syncthreads();
        s[t] += u;
        __syncthreads();
    }
    if (idx < NN) rowstart[idx] = s[t] - v + bpre[blockIdx.x];
    if (idx == 0) rowstart[NN] = EE;
}

// scatter edges into dst-sorted record array {src, normalized weight} (8 B each)
__global__ void fill_kernel(const int* __restrict__ ei, const float* __restrict__ ew,
                            const float* __restrict__ dinv, const int* __restrict__ rowstart,
                            int* __restrict__ cnt2, uint2* __restrict__ eprec) {
    int e = blockIdx.x * blockDim.x + threadIdx.x;
    if (e >= EE) return;
    int s = ei[e], d = ei[EE + e];
    int idx = rowstart[d] + atomicAdd(&cnt2[d], 1);
    float w = dinv[s] * ew[e] * dinv[d];
    eprec[idx] = make_uint2((unsigned)s, __float_as_uint(w));
}

// ---------------- weight convert: Wt[n][k] bf16, combined [Wg | Ws], padded rows = 0

__global__ void wconv_kernel(const float* __restrict__ Wg, const float* __restrict__ Ws,
                             unsigned short* __restrict__ Wt, int K, int Fo, int N2) {
    int idx = blockIdx.x * 256 + threadIdx.x;
    if (idx >= N2 * K) return;
    int n = idx / K, k = idx - n * K;
    float v = 0.f;
    if (n < Fo) v = Wg[(size_t)k * Fo + n];
    else if (n < 2 * Fo) v = Ws[(size_t)k * Fo + (n - Fo)];
    Wt[idx] = f2b(v);
}

// ---------------- MFMA dual GEMM ----------------

__device__ inline uint2 load4bf(const float* p) {
    float4 v = *reinterpret_cast<const float4*>(p);
    uint2 r;
    r.x = pack2(v.x, v.y);
    r.y = pack2(v.z, v.w);
    return r;
}
__device__ inline uint2 load4bf(const unsigned short* p) {
    return *reinterpret_cast<const uint2*>(p);
}

template <typename TA>
__global__ __launch_bounds__(256) void gemm_mfma(const TA* __restrict__ A,
                                                 const unsigned short* __restrict__ Wt,
                                                 const float* __restrict__ bias,
                                                 unsigned short* __restrict__ Cg,
                                                 float* __restrict__ Cs,
                                                 int M, int K, int Fo) {
    __shared__ unsigned short sA[128 * 72];
    __shared__ unsigned short sB[128 * 72];

    const int t = threadIdx.x;
    const int lane = t & 63;
    const int wave = t >> 6;
    const int wm = wave >> 1, wn = wave & 1;
    const int l15 = lane & 15, quad = lane >> 4;
    const int row0 = blockIdx.x * 128;
    const int colbase = blockIdx.y * 128;

    fx4 acc[4][4];
#pragma unroll
    for (int r = 0; r < 4; ++r)
#pragma unroll
        for (int c = 0; c < 4; ++c) acc[r][c] = (fx4){0.f, 0.f, 0.f, 0.f};

    for (int kc = 0; kc < K; kc += 64) {
#pragma unroll
        for (int j = 0; j < 8; ++j) {
            int i = t + j * 256;
            int row = i >> 4, c4 = (i & 15) * 4;
            int grow = row0 + row;
            uint2 v = make_uint2(0u, 0u);
            if (grow < M) v = load4bf(A + (size_t)grow * K + kc + c4);
            *reinterpret_cast<uint2*>(&sA[row * 72 + c4]) = v;
        }
#pragma unroll
        for (int j = 0; j < 8; ++j) {
            int i = t + j * 256;
            int row = i >> 4, c4 = (i & 15) * 4;
            uint2 v = *reinterpret_cast<const uint2*>(Wt + (size_t)(colbase + row) * K + kc + c4);
            *reinterpret_cast<uint2*>(&sB[row * 72 + c4]) = v;
        }
        __syncthreads();

#pragma unroll
        for (int kh = 0; kh < 2; ++kh) {
            short8 a[4], b[4];
#pragma unroll
            for (int r = 0; r < 4; ++r)
                a[r] = *reinterpret_cast<const short8*>(&sA[(wm * 64 + r * 16 + l15) * 72 + kh * 32 + quad * 8]);
#pragma unroll
            for (int c = 0; c < 4; ++c)
                b[c] = *reinterpret_cast<const short8*>(&sB[(wn * 64 + c * 16 + l15) * 72 + kh * 32 + quad * 8]);
#pragma unroll
            for (int r = 0; r < 4; ++r)
#pragma unroll
                for (int c = 0; c < 4; ++c)
                    acc[r][c] = __builtin_amdgcn_mfma_f32_16x16x32_bf16(a[r], b[c], acc[r][c], 0, 0, 0);
        }
        __syncthreads();
    }

    // epilogue (C/D layout: col = lane&15, row = quad*4 + reg)
#pragma unroll
    for (int c = 0; c < 4; ++c) {
        int f = colbase + wn * 64 + c * 16 + l15;
        if (f >= 2 * Fo) continue;
        bool isG = (f < Fo);
        int col = isG ? f : f - Fo;
        float badd = isG ? 0.f : bias[col];
#pragma unroll
        for (int r = 0; r < 4; ++r) {
#pragma unroll
            for (int reg = 0; reg < 4; ++reg) {
                int row = row0 + wm * 64 + r * 16 + quad * 4 + reg;
                if (row < M) {
                    float v = acc[r][c][reg] + badd;
                    if (isG)
                        Cg[(size_t)row * Fo + col] = f2b(v);
                    else
                        Cs[(size_t)row * Fo + col] = v;
                }
            }
        }
    }
}

// ---------------- pull aggregation + fused BN/ReLU, Fo=128, bf16 in/out

template <bool RELU>
__global__ __launch_bounds__(256) void agg128_kernel(
    const int* __restrict__ rowstart, const uint2* __restrict__ eprec,
    const unsigned* __restrict__ hw, const float* __restrict__ selfC,
    const float* __restrict__ g, const float* __restrict__ be,
    const float* __restrict__ mu, const float* __restrict__ va,
    unsigned* __restrict__ out) {
    int wave = threadIdx.x >> 6;
    int lane = threadIdx.x & 63;
    int n = blockIdx.x * 4 + wave;
    if (n >= NN) return;
    float2 sc = reinterpret_cast<const float2*>(selfC)[n * 64 + lane];
    float acc0 = sc.x, acc1 = sc.y;
    int beg = rowstart[n], end = rowstart[n + 1];
    int i = beg;
    for (; i + 4 <= end; i += 4) {
        uint2 e0 = eprec[i], e1 = eprec[i + 1], e2 = eprec[i + 2], e3 = eprec[i + 3];
        unsigned v0 = hw[e0.x * 64u + lane];
        unsigned v1 = hw[e1.x * 64u + lane];
        unsigned v2 = hw[e2.x * 64u + lane];
        unsigned v3 = hw[e3.x * 64u + lane];
        float w0 = __uint_as_float(e0.y), w1 = __uint_as_float(e1.y);
        float w2 = __uint_as_float(e2.y), w3 = __uint_as_float(e3.y);
        acc0 += blo(v0) * w0; acc1 += bhi(v0) * w0;
        acc0 += blo(v1) * w1; acc1 += bhi(v1) * w1;
        acc0 += blo(v2) * w2; acc1 += bhi(v2) * w2;
        acc0 += blo(v3) * w3; acc1 += bhi(v3) * w3;
    }
    for (; i < end; ++i) {
        uint2 e = eprec[i];
        unsigned v = hw[e.x * 64u + lane];
        float w = __uint_as_float(e.y);
        acc0 += blo(v) * w; acc1 += bhi(v) * w;
    }
    float2 m2 = reinterpret_cast<const float2*>(mu)[lane];
    float2 v2f = reinterpret_cast<const float2*>(va)[lane];
    float2 g2 = reinterpret_cast<const float2*>(g)[lane];
    float2 b2 = reinterpret_cast<const float2*>(be)[lane];
    float r0 = (acc0 - m2.x) * rsqrtf(v2f.x + EPSV) * g2.x + b2.x;
    float r1 = (acc1 - m2.y) * rsqrtf(v2f.y + EPSV) * g2.y + b2.y;
    if (RELU) {
        r0 = fmaxf(r0, 0.f);
        r1 = fmaxf(r1, 0.f);
    }
    out[n * 64 + lane] = pack2(r0, r1);
}

// ---------------- final layer aggregation, Fo=40 (20 dwords/row), fp32 out

__global__ __launch_bounds__(256) void agg40_kernel(
    const int* __restrict__ rowstart, const uint2* __restrict__ eprec,
    const unsigned* __restrict__ hw, const float* __restrict__ selfC,
    const float* __restrict__ g, const float* __restrict__ be,
    const float* __restrict__ mu, const float* __restrict__ va,
    float* __restrict__ out) {
    int wave = threadIdx.x >> 6;
    int lane = threadIdx.x & 63;
    int n = blockIdx.x * 4 + wave;
    if (n >= NN) return;
    int grp = lane / 20;        // 0..3 (grp 3 idle in loop)
    int fl = lane - grp * 20;   // 0..19
    float acc0 = 0.f, acc1 = 0.f;
    int beg = rowstart[n], end = rowstart[n + 1];
    if (grp < 3) {
        for (int i = beg + grp; i < end; i += 3) {
            uint2 e = eprec[i];
            unsigned v = hw[e.x * 20u + fl];
            float w = __uint_as_float(e.y);
            acc0 += blo(v) * w;
            acc1 += bhi(v) * w;
        }
    }
    acc0 += __shfl(acc0, lane + 20) + __shfl(acc0, lane + 40);
    acc1 += __shfl(acc1, lane + 20) + __shfl(acc1, lane + 40);
    if (lane < 20) {
        int f0 = lane * 2;
        float2 sc = reinterpret_cast<const float2*>(selfC)[n * 20 + lane];
        acc0 += sc.x;
        acc1 += sc.y;
        float2 m2 = reinterpret_cast<const float2*>(mu)[lane];
        float2 v2f = reinterpret_cast<const float2*>(va)[lane];
        float2 g2 = reinterpret_cast<const float2*>(g)[lane];
        float2 b2 = reinterpret_cast<const float2*>(be)[lane];
        float r0 = (acc0 - m2.x) * rsqrtf(v2f.x + EPSV) * g2.x + b2.x;
        float r1 = (acc1 - m2.y) * rsqrtf(v2f.y + EPSV) * g2.y + b2.y;
        *reinterpret_cast<float2*>(&out[(size_t)n * 40 + f0]) = make_float2(r0, r1);
    }
}

// ---------------- launch ----------------

extern "C" void kernel_launch(void* const* d_in, const int* in_sizes, int n_in,
                              void* d_out, int out_size, void* d_ws, size_t ws_size,
                              hipStream_t stream) {
    const float* x = (const float*)d_in[0];
    const int* ei = (const int*)d_in[1];
    const float* ew = (const float*)d_in[2];

    const float* wg[3]  = {(const float*)d_in[3],  (const float*)d_in[10], (const float*)d_in[17]};
    const float* wsf[3] = {(const float*)d_in[4],  (const float*)d_in[11], (const float*)d_in[18]};
    const float* bs[3]  = {(const float*)d_in[5],  (const float*)d_in[12], (const float*)d_in[19]};
    const float* gm[3]  = {(const float*)d_in[6],  (const float*)d_in[13], (const float*)d_in[20]};
    const float* bt[3]  = {(const float*)d_in[7],  (const float*)d_in[14], (const float*)d_in[21]};
    const float* mu[3]  = {(const float*)d_in[8],  (const float*)d_in[15], (const float*)d_in[22]};
    const float* vr[3]  = {(const float*)d_in[9],  (const float*)d_in[16], (const float*)d_in[23]};

    // workspace layout (float-sized slots); ws >= 68 MB (proven by R2 usage)
    float* W = (float*)d_ws;
    unsigned long long* cnt64 = (unsigned long long*)W;      // 50000 u64 (100096 slots)
    float* dinv     = W + 100096;                // 50048
    int*   cnt2     = (int*)(W + 150144);        // 50048
    int*   bsum     = (int*)(W + 200192);        // 64
    int*   bpre     = (int*)(W + 200256);        // 64
    int*   rowstart = (int*)(W + 200320);        // 50112
    uint2* eprec    = (uint2*)(W + 250432);      // 1,000,000 records (2M slots)
    unsigned short* Wt1 = (unsigned short*)(W + 2250432);    // 256x256 bf16 (32768 slots)
    unsigned short* Wt2 = (unsigned short*)(W + 2283200);    // 256x128 bf16 (16384 slots)
    unsigned short* Wt3 = (unsigned short*)(W + 2299584);    // 128x128 bf16 (8192 slots)
    unsigned short* bufHW = (unsigned short*)(W + 2307776);  // 50000x128 bf16 (3.2M slots)
    float* bufS     = W + 5507776;               // 50000x128 fp32 (6.4M)
    unsigned short* bufH = (unsigned short*)(W + 11907776);  // 50000x128 bf16 (3.2M slots)
    // end = 15,107,776 floats = 60.4 MB

    const int B = 256;
    const int SB = 49;  // scan blocks of 1024

    // preprocessing: degree norm + dst-sorted CSR
    zero_kernel<<<(200192 + B - 1) / B, B, 0, stream>>>(W, 200192);  // cnt64, dinv, cnt2
    cntdeg_kernel<<<(EE + B - 1) / B, B, 0, stream>>>(ei, ew, cnt64);
    dinvsum_kernel<<<SB, 1024, 0, stream>>>((const uint2*)cnt64, dinv, bsum);
    scanB_kernel<<<1, 64, 0, stream>>>(bsum, bpre, SB);
    scanC_kernel<<<SB, 1024, 0, stream>>>((const uint2*)cnt64, bpre, rowstart);
    fill_kernel<<<(EE + B - 1) / B, B, 0, stream>>>(ei, ew, dinv, rowstart, cnt2, eprec);

    // weight conversion
    wconv_kernel<<<(256 * 256 + B - 1) / B, B, 0, stream>>>(wg[0], wsf[0], Wt1, 256, 128, 256);
    wconv_kernel<<<(256 * 128 + B - 1) / B, B, 0, stream>>>(wg[1], wsf[1], Wt2, 128, 128, 256);
    wconv_kernel<<<(128 * 128 + B - 1) / B, B, 0, stream>>>(wg[2], wsf[2], Wt3, 128, 40, 128);

    const int aggGrid = (NN + 3) / 4;
    dim3 g2((NN + 127) / 128, 2), g1((NN + 127) / 128, 1);

    // layer 1: x fp32 [N,256] -> 128
    gemm_mfma<float><<<g2, B, 0, stream>>>(x, Wt1, bs[0], bufHW, bufS, NN, 256, 128);
    agg128_kernel<true><<<aggGrid, B, 0, stream>>>(rowstart, eprec, (const unsigned*)bufHW,
                                                   bufS, gm[0], bt[0], mu[0], vr[0], (unsigned*)bufH);

    // layer 2: h bf16 [N,128] -> 128
    gemm_mfma<unsigned short><<<g2, B, 0, stream>>>(bufH, Wt2, bs[1], bufHW, bufS, NN, 128, 128);
    agg128_kernel<true><<<aggGrid, B, 0, stream>>>(rowstart, eprec, (const unsigned*)bufHW,
                                                   bufS, gm[1], bt[1], mu[1], vr[1], (unsigned*)bufH);

    // layer 3: h bf16 [N,128] -> 40 (padded to 128 cols), fp32 out
    gemm_mfma<unsigned short><<<g1, B, 0, stream>>>(bufH, Wt3, bs[2], bufHW, bufS, NN, 128, 40);
    agg40_kernel<<<aggGrid, B, 0, stream>>>(rowstart, eprec, (const unsigned*)bufHW,
                                            bufS, gm[2], bt[2], mu[2], vr[2], (float*)d_out);
}

// Round 9
// 461.560 us; speedup vs baseline: 9.9697x; 1.0436x over previous
//
#include <hip/hip_runtime.h>
#include <hip/hip_bf16.h>

#define NN 50000
#define EE 1000000
static constexpr float EPSV = 1e-3f;
static constexpr float FIXSCALE = 16777216.f;  // 2^24

typedef __attribute__((ext_vector_type(8))) short short8;
typedef __attribute__((ext_vector_type(4))) float fx4;

__device__ inline float blo(unsigned u) { return __uint_as_float(u << 16); }
__device__ inline float bhi(unsigned u) { return __uint_as_float(u & 0xffff0000u); }
__device__ inline unsigned short f2b(float f) {
    __hip_bfloat16 h = __float2bfloat16(f);
    return *(unsigned short*)&h;
}
__device__ inline unsigned pack2(float a, float b) {
    return (unsigned)f2b(a) | ((unsigned)f2b(b) << 16);
}

// async global->LDS DMA, 16 B per lane: lane i's data lands at ldsbase + i*16.
// ldsbase must be wave-uniform.
__device__ inline void gload_lds16(const unsigned short* g, unsigned short* ldsbase) {
    __builtin_amdgcn_global_load_lds(
        (const __attribute__((address_space(1))) unsigned int*)(const void*)g,
        (__attribute__((address_space(3))) unsigned int*)(void*)ldsbase, 16, 0, 0);
}

// ---------------- preprocessing ----------------

__global__ void zero_kernel(float* p, int n) {
    int i = blockIdx.x * blockDim.x + threadIdx.x;
    if (i < n) p[i] = 0.f;
}

// one uint64 atomic per edge: high32 = count, low32 = deg in 8.24 fixed point
__global__ void cntdeg_kernel(const int* __restrict__ ei, const float* __restrict__ ew,
                              unsigned long long* __restrict__ cnt64) {
    int e = blockIdx.x * blockDim.x + threadIdx.x;
    if (e < EE) {
        int d = ei[EE + e];
        unsigned fx = __float2uint_rn(ew[e] * FIXSCALE);
        atomicAdd(&cnt64[d], 0x100000000ull | (unsigned long long)fx);
    }
}

__global__ __launch_bounds__(1024) void dinvsum_kernel(const uint2* __restrict__ cnt64,
                                                       float* __restrict__ dinv,
                                                       int* __restrict__ bsum) {
    __shared__ int s[1024];
    const int t = threadIdx.x;
    int idx = blockIdx.x * 1024 + t;
    uint2 cv = make_uint2(0u, 0u);
    if (idx < NN) cv = cnt64[idx];
    float deg = (float)cv.x * (1.f / FIXSCALE);
    if (idx < NN) dinv[idx] = (deg > 0.f) ? rsqrtf(deg) : 0.f;
    s[t] = (int)cv.y;
    __syncthreads();
#pragma unroll
    for (int off = 512; off > 0; off >>= 1) {
        if (t < off) s[t] += s[t + off];
        __syncthreads();
    }
    if (t == 0) bsum[blockIdx.x] = s[0];
}

__global__ __launch_bounds__(64) void scanB_kernel(const int* __restrict__ bsum,
                                                   int* __restrict__ bpre, int nb) {
    int t = threadIdx.x;
    int v = (t < nb) ? bsum[t] : 0;
    int own = v;
#pragma unroll
    for (int off = 1; off < 64; off <<= 1) {
        int u = __shfl_up(v, off);
        if (t >= off) v += u;
    }
    if (t < nb) bpre[t] = v - own;
}

__global__ __launch_bounds__(1024) void scanC_kernel(const uint2* __restrict__ cnt64,
                                                     const int* __restrict__ bpre,
                                                     int* __restrict__ rowstart) {
    __shared__ int s[1024];
    const int t = threadIdx.x;
    int idx = blockIdx.x * 1024 + t;
    int v = (idx < NN) ? (int)cnt64[idx].y : 0;
    s[t] = v;
    __syncthreads();
#pragma unroll
    for (int off = 1; off < 1024; off <<= 1) {
        int u = (t >= off) ? s[t - off] : 0;
        __syncthreads();
        s[t] += u;
        __syncthreads();
    }
    if (idx < NN) rowstart[idx] = s[t] - v + bpre[blockIdx.x];
    if (idx == 0) rowstart[NN] = EE;
}

__global__ void fill_kernel(const int* __restrict__ ei, const float* __restrict__ ew,
                            const float* __restrict__ dinv, const int* __restrict__ rowstart,
                            int* __restrict__ cnt2, uint2* __restrict__ eprec) {
    int e = blockIdx.x * blockDim.x + threadIdx.x;
    if (e >= EE) return;
    int s = ei[e], d = ei[EE + e];
    int idx = rowstart[d] + atomicAdd(&cnt2[d], 1);
    float w = dinv[s] * ew[e] * dinv[d];
    eprec[idx] = make_uint2((unsigned)s, __float_as_uint(w));
}

// ---------------- x fp32 -> bf16 ----------------

__global__ void xconv_kernel(const float4* __restrict__ x, uint2* __restrict__ xb, int n4) {
    int i = blockIdx.x * 256 + threadIdx.x;
    if (i < n4) {
        float4 v = x[i];
        xb[i] = make_uint2(pack2(v.x, v.y), pack2(v.z, v.w));
    }
}

// ---------------- weight convert: Wt[n][k] bf16, combined [Wg | Ws], pad rows = 0

__global__ void wconv_kernel(const float* __restrict__ Wg, const float* __restrict__ Ws,
                             unsigned short* __restrict__ Wt, int K, int Fo, int N2) {
    int idx = blockIdx.x * 256 + threadIdx.x;
    if (idx >= N2 * K) return;
    int n = idx / K, k = idx - n * K;
    float v = 0.f;
    if (n < Fo) v = Wg[(size_t)k * Fo + n];
    else if (n < 2 * Fo) v = Ws[(size_t)k * Fo + (n - Fo)];
    Wt[idx] = f2b(v);
}

// ---------------- MFMA dual GEMM, async LDS staging ----------------
// Block tile 128x128, 4 waves 2x2, wave tile 64x64 (4x4 of 16x16x32 bf16 MFMA).
// LDS in fragment order: chunk c=(rowblk*2+kh), 1024 B each; within a chunk
// lane l's 16B slot holds (row = rowblk*16 + (l&15), k = kh*32 + (l>>4)*8 .. +8).
// Staged with global_load_lds (wave-uniform chunk base; HW adds lane*16).
// ds_read_b128 back is stride-1 conflict-free.

__global__ __launch_bounds__(256) void gemm_mfma(const unsigned short* __restrict__ Ab,
                                                 const unsigned short* __restrict__ Wt,
                                                 const float* __restrict__ bias,
                                                 unsigned short* __restrict__ Cg,
                                                 unsigned short* __restrict__ Cs,
                                                 int M, int K, int Fo) {
    __shared__ unsigned short sA[128 * 64];
    __shared__ unsigned short sB[128 * 64];

    const int t = threadIdx.x;
    const int lane = t & 63;
    const int wave = t >> 6;
    const int wm = wave >> 1, wn = wave & 1;
    const int l15 = lane & 15, quad = lane >> 4;
    const int row0 = blockIdx.x * 128;
    const int colbase = blockIdx.y * 128;

    fx4 acc[4][4];
#pragma unroll
    for (int r = 0; r < 4; ++r)
#pragma unroll
        for (int c = 0; c < 4; ++c) acc[r][c] = (fx4){0.f, 0.f, 0.f, 0.f};

    for (int kc = 0; kc < K; kc += 64) {
        // stage A+B: each wave issues 4+4 async 16B/lane chunk DMAs
#pragma unroll
        for (int j = 0; j < 4; ++j) {
            int c = wave * 4 + j;              // chunk 0..15
            int rb = c >> 1, kh = c & 1;
            int ar = row0 + rb * 16 + l15;
            if (ar >= M) ar = M - 1;           // clamp: dup loads, C rows >= M unwritten
            int ak = kc + kh * 32 + quad * 8;
            gload_lds16(Ab + (size_t)ar * K + ak, sA + c * 512);
            int br = colbase + rb * 16 + l15;  // always < N2 (Wt padded)
            gload_lds16(Wt + (size_t)br * K + ak, sB + c * 512);
        }
        __syncthreads();  // drains vmcnt(0): DMA complete

#pragma unroll
        for (int kh = 0; kh < 2; ++kh) {
            short8 a[4], b[4];
#pragma unroll
            for (int r = 0; r < 4; ++r)
                a[r] = *reinterpret_cast<const short8*>(&sA[((wm * 4 + r) * 2 + kh) * 512 + lane * 8]);
#pragma unroll
            for (int c = 0; c < 4; ++c)
                b[c] = *reinterpret_cast<const short8*>(&sB[((wn * 4 + c) * 2 + kh) * 512 + lane * 8]);
#pragma unroll
            for (int r = 0; r < 4; ++r)
#pragma unroll
                for (int c = 0; c < 4; ++c)
                    acc[r][c] = __builtin_amdgcn_mfma_f32_16x16x32_bf16(a[r], b[c], acc[r][c], 0, 0, 0);
        }
        __syncthreads();
    }

    // epilogue (C/D layout: col = lane&15, row = quad*4 + reg), both outputs bf16
#pragma unroll
    for (int c = 0; c < 4; ++c) {
        int f = colbase + wn * 64 + c * 16 + l15;
        if (f >= 2 * Fo) continue;
        bool isG = (f < Fo);
        int col = isG ? f : f - Fo;
        float badd = isG ? 0.f : bias[col];
        unsigned short* base = isG ? Cg : Cs;
#pragma unroll
        for (int r = 0; r < 4; ++r) {
#pragma unroll
            for (int reg = 0; reg < 4; ++reg) {
                int row = row0 + wm * 64 + r * 16 + quad * 4 + reg;
                if (row < M) base[(size_t)row * Fo + col] = f2b(acc[r][c][reg] + badd);
            }
        }
    }
}

// ---------------- pull aggregation + fused BN/ReLU, Fo=128, bf16 in/out

template <bool RELU>
__global__ __launch_bounds__(256) void agg128_kernel(
    const int* __restrict__ rowstart, const uint2* __restrict__ eprec,
    const unsigned* __restrict__ hw, const unsigned* __restrict__ selfC,
    const float* __restrict__ g, const float* __restrict__ be,
    const float* __restrict__ mu, const float* __restrict__ va,
    unsigned* __restrict__ out) {
    int wave = threadIdx.x >> 6;
    int lane = threadIdx.x & 63;
    int n = blockIdx.x * 4 + wave;
    if (n >= NN) return;
    unsigned scp = selfC[n * 64 + lane];
    float acc0 = blo(scp), acc1 = bhi(scp);
    int beg = rowstart[n], end = rowstart[n + 1];
    int i = beg;
    for (; i + 4 <= end; i += 4) {
        uint2 e0 = eprec[i], e1 = eprec[i + 1], e2 = eprec[i + 2], e3 = eprec[i + 3];
        unsigned v0 = hw[e0.x * 64u + lane];
        unsigned v1 = hw[e1.x * 64u + lane];
        unsigned v2 = hw[e2.x * 64u + lane];
        unsigned v3 = hw[e3.x * 64u + lane];
        float w0 = __uint_as_float(e0.y), w1 = __uint_as_float(e1.y);
        float w2 = __uint_as_float(e2.y), w3 = __uint_as_float(e3.y);
        acc0 += blo(v0) * w0; acc1 += bhi(v0) * w0;
        acc0 += blo(v1) * w1; acc1 += bhi(v1) * w1;
        acc0 += blo(v2) * w2; acc1 += bhi(v2) * w2;
        acc0 += blo(v3) * w3; acc1 += bhi(v3) * w3;
    }
    for (; i < end; ++i) {
        uint2 e = eprec[i];
        unsigned v = hw[e.x * 64u + lane];
        float w = __uint_as_float(e.y);
        acc0 += blo(v) * w; acc1 += bhi(v) * w;
    }
    float2 m2 = reinterpret_cast<const float2*>(mu)[lane];
    float2 v2f = reinterpret_cast<const float2*>(va)[lane];
    float2 g2 = reinterpret_cast<const float2*>(g)[lane];
    float2 b2 = reinterpret_cast<const float2*>(be)[lane];
    float r0 = (acc0 - m2.x) * rsqrtf(v2f.x + EPSV) * g2.x + b2.x;
    float r1 = (acc1 - m2.y) * rsqrtf(v2f.y + EPSV) * g2.y + b2.y;
    if (RELU) {
        r0 = fmaxf(r0, 0.f);
        r1 = fmaxf(r1, 0.f);
    }
    out[n * 64 + lane] = pack2(r0, r1);
}

// ---------------- final layer aggregation, Fo=40, fp32 out

__global__ __launch_bounds__(256) void agg40_kernel(
    const int* __restrict__ rowstart, const uint2* __restrict__ eprec,
    const unsigned* __restrict__ hw, const unsigned* __restrict__ selfC,
    const float* __restrict__ g, const float* __restrict__ be,
    const float* __restrict__ mu, const float* __restrict__ va,
    float* __restrict__ out) {
    int wave = threadIdx.x >> 6;
    int lane = threadIdx.x & 63;
    int n = blockIdx.x * 4 + wave;
    if (n >= NN) return;
    int grp = lane / 20;
    int fl = lane - grp * 20;
    float acc0 = 0.f, acc1 = 0.f;
    int beg = rowstart[n], end = rowstart[n + 1];
    if (grp < 3) {
        for (int i = beg + grp; i < end; i += 3) {
            uint2 e = eprec[i];
            unsigned v = hw[e.x * 20u + fl];
            float w = __uint_as_float(e.y);
            acc0 += blo(v) * w;
            acc1 += bhi(v) * w;
        }
    }
    acc0 += __shfl(acc0, lane + 20) + __shfl(acc0, lane + 40);
    acc1 += __shfl(acc1, lane + 20) + __shfl(acc1, lane + 40);
    if (lane < 20) {
        int f0 = lane * 2;
        unsigned scp = selfC[n * 20 + lane];
        acc0 += blo(scp);
        acc1 += bhi(scp);
        float2 m2 = reinterpret_cast<const float2*>(mu)[lane];
        float2 v2f = reinterpret_cast<const float2*>(va)[lane];
        float2 g2 = reinterpret_cast<const float2*>(g)[lane];
        float2 b2 = reinterpret_cast<const float2*>(be)[lane];
        float r0 = (acc0 - m2.x) * rsqrtf(v2f.x + EPSV) * g2.x + b2.x;
        float r1 = (acc1 - m2.y) * rsqrtf(v2f.y + EPSV) * g2.y + b2.y;
        *reinterpret_cast<float2*>(&out[(size_t)n * 40 + f0]) = make_float2(r0, r1);
    }
}

// ---------------- launch ----------------

extern "C" void kernel_launch(void* const* d_in, const int* in_sizes, int n_in,
                              void* d_out, int out_size, void* d_ws, size_t ws_size,
                              hipStream_t stream) {
    const float* x = (const float*)d_in[0];
    const int* ei = (const int*)d_in[1];
    const float* ew = (const float*)d_in[2];

    const float* wg[3]  = {(const float*)d_in[3],  (const float*)d_in[10], (const float*)d_in[17]};
    const float* wsf[3] = {(const float*)d_in[4],  (const float*)d_in[11], (const float*)d_in[18]};
    const float* bs[3]  = {(const float*)d_in[5],  (const float*)d_in[12], (const float*)d_in[19]};
    const float* gm[3]  = {(const float*)d_in[6],  (const float*)d_in[13], (const float*)d_in[20]};
    const float* bt[3]  = {(const float*)d_in[7],  (const float*)d_in[14], (const float*)d_in[21]};
    const float* mu[3]  = {(const float*)d_in[8],  (const float*)d_in[15], (const float*)d_in[22]};
    const float* vr[3]  = {(const float*)d_in[9],  (const float*)d_in[16], (const float*)d_in[23]};

    // workspace layout (float-sized slots), total 60.4 MB, regions disjoint
    // (except bufH aliasing xb intentionally: xb dead after gemm1)
    float* W = (float*)d_ws;
    unsigned long long* cnt64 = (unsigned long long*)W;       // [0, 100096)
    float* dinv     = W + 100096;                 // [100096, 150144)
    int*   cnt2     = (int*)(W + 150144);         // [150144, 200192)
    int*   bsum     = (int*)(W + 200192);         // [200192, 200256)
    int*   bpre     = (int*)(W + 200256);         // [200256, 200320)
    int*   rowstart = (int*)(W + 200320);         // [200320, 250432)
    uint2* eprec    = (uint2*)(W + 250432);       // [250432, 2250432)  1M x 8B
    unsigned short* Wt1 = (unsigned short*)(W + 2250432);     // [2250432, 2283200)  256x256 bf16
    unsigned short* Wt2 = (unsigned short*)(W + 2283200);     // [2283200, 2299584)  256x128 bf16
    unsigned short* Wt3 = (unsigned short*)(W + 2299584);     // [2299584, 2307776)  128x128 bf16
    unsigned short* xb  = (unsigned short*)(W + 2307776);     // [2307776, 8707776)  50000x256 bf16
    unsigned short* bufH = (unsigned short*)(W + 2307776);    // aliases xb
    unsigned short* bufHW = (unsigned short*)(W + 8707776);   // [8707776, 11907776) 50000x128 bf16
    unsigned short* bufSb = (unsigned short*)(W + 11907776);  // [11907776, 15107776) 50000x128 bf16

    const int B = 256;
    const int SB = 49;

    // preprocessing: degree norm + dst-sorted CSR
    zero_kernel<<<(200192 + B - 1) / B, B, 0, stream>>>(W, 200192);
    cntdeg_kernel<<<(EE + B - 1) / B, B, 0, stream>>>(ei, ew, cnt64);
    dinvsum_kernel<<<SB, 1024, 0, stream>>>((const uint2*)cnt64, dinv, bsum);
    scanB_kernel<<<1, 64, 0, stream>>>(bsum, bpre, SB);
    scanC_kernel<<<SB, 1024, 0, stream>>>((const uint2*)cnt64, bpre, rowstart);
    fill_kernel<<<(EE + B - 1) / B, B, 0, stream>>>(ei, ew, dinv, rowstart, cnt2, eprec);

    // conversions
    xconv_kernel<<<(NN * 64 + B - 1) / B, B, 0, stream>>>((const float4*)x, (uint2*)xb, NN * 64);
    wconv_kernel<<<(256 * 256 + B - 1) / B, B, 0, stream>>>(wg[0], wsf[0], Wt1, 256, 128, 256);
    wconv_kernel<<<(256 * 128 + B - 1) / B, B, 0, stream>>>(wg[1], wsf[1], Wt2, 128, 128, 256);
    wconv_kernel<<<(128 * 128 + B - 1) / B, B, 0, stream>>>(wg[2], wsf[2], Wt3, 128, 40, 128);

    const int aggGrid = (NN + 3) / 4;
    dim3 g2((NN + 127) / 128, 2), g1((NN + 127) / 128, 1);

    // layer 1: xb bf16 [N,256] -> 128
    gemm_mfma<<<g2, B, 0, stream>>>(xb, Wt1, bs[0], bufHW, bufSb, NN, 256, 128);
    agg128_kernel<true><<<aggGrid, B, 0, stream>>>(rowstart, eprec, (const unsigned*)bufHW,
                                                   (const unsigned*)bufSb, gm[0], bt[0], mu[0], vr[0],
                                                   (unsigned*)bufH);

    // layer 2: h bf16 [N,128] -> 128
    gemm_mfma<<<g2, B, 0, stream>>>(bufH, Wt2, bs[1], bufHW, bufSb, NN, 128, 128);
    agg128_kernel<true><<<aggGrid, B, 0, stream>>>(rowstart, eprec, (const unsigned*)bufHW,
                                                   (const unsigned*)bufSb, gm[1], bt[1], mu[1], vr[1],
                                                   (unsigned*)bufH);

    // layer 3: h bf16 [N,128] -> 40 (cols padded to 128), fp32 out
    gemm_mfma<<<g1, B, 0, stream>>>(bufH, Wt3, bs[2], bufHW, bufSb, NN, 128, 40);
    agg40_kernel<<<aggGrid, B, 0, stream>>>(rowstart, eprec, (const unsigned*)bufHW,
                                            (const unsigned*)bufSb, gm[2], bt[2], mu[2], vr[2],
                                            (float*)d_out);
}

// Round 10
// 432.473 us; speedup vs baseline: 10.6402x; 1.0673x over previous
//
#include <hip/hip_runtime.h>
#include <hip/hip_bf16.h>

#define NN 50000
#define EE 1000000
static constexpr float EPSV = 1e-3f;
static constexpr float FIXSCALE = 16777216.f;  // 2^24

typedef __attribute__((ext_vector_type(8))) short short8;
typedef __attribute__((ext_vector_type(4))) float fx4;

__device__ inline float blo(unsigned u) { return __uint_as_float(u << 16); }
__device__ inline float bhi(unsigned u) { return __uint_as_float(u & 0xffff0000u); }
__device__ inline unsigned short f2b(float f) {
    __hip_bfloat16 h = __float2bfloat16(f);
    return *(unsigned short*)&h;
}
__device__ inline unsigned pack2(float a, float b) {
    return (unsigned)f2b(a) | ((unsigned)f2b(b) << 16);
}

// async global->LDS DMA, 16 B per lane: lane i's data lands at ldsbase + i*16.
__device__ inline void gload_lds16(const unsigned short* g, unsigned short* ldsbase) {
    __builtin_amdgcn_global_load_lds(
        (const __attribute__((address_space(1))) unsigned int*)(const void*)g,
        (__attribute__((address_space(3))) unsigned int*)(void*)ldsbase, 16, 0, 0);
}

// ---------------- preprocessing ----------------

__global__ void zero_kernel(float* p, int n) {
    int i = blockIdx.x * blockDim.x + threadIdx.x;
    if (i < n) p[i] = 0.f;
}

// one uint64 atomic per edge: high32 = count, low32 = deg in 8.24 fixed point.
// The returned old value's high word is this edge's rank within its dst.
__global__ void cntdeg_kernel(const int* __restrict__ ei, const float* __restrict__ ew,
                              unsigned long long* __restrict__ cnt64,
                              unsigned* __restrict__ rank) {
    int e = blockIdx.x * blockDim.x + threadIdx.x;
    if (e < EE) {
        int d = ei[EE + e];
        unsigned fx = __float2uint_rn(ew[e] * FIXSCALE);
        unsigned long long old = atomicAdd(&cnt64[d], 0x100000000ull | (unsigned long long)fx);
        rank[e] = (unsigned)(old >> 32);
    }
}

__global__ __launch_bounds__(1024) void dinvsum_kernel(const uint2* __restrict__ cnt64,
                                                       float* __restrict__ dinv,
                                                       int* __restrict__ bsum) {
    __shared__ int s[1024];
    const int t = threadIdx.x;
    int idx = blockIdx.x * 1024 + t;
    uint2 cv = make_uint2(0u, 0u);
    if (idx < NN) cv = cnt64[idx];
    float deg = (float)cv.x * (1.f / FIXSCALE);
    if (idx < NN) dinv[idx] = (deg > 0.f) ? rsqrtf(deg) : 0.f;
    s[t] = (int)cv.y;
    __syncthreads();
#pragma unroll
    for (int off = 512; off > 0; off >>= 1) {
        if (t < off) s[t] += s[t + off];
        __syncthreads();
    }
    if (t == 0) bsum[blockIdx.x] = s[0];
}

__global__ __launch_bounds__(64) void scanB_kernel(const int* __restrict__ bsum,
                                                   int* __restrict__ bpre, int nb) {
    int t = threadIdx.x;
    int v = (t < nb) ? bsum[t] : 0;
    int own = v;
#pragma unroll
    for (int off = 1; off < 64; off <<= 1) {
        int u = __shfl_up(v, off);
        if (t >= off) v += u;
    }
    if (t < nb) bpre[t] = v - own;
}

__global__ __launch_bounds__(1024) void scanC_kernel(const uint2* __restrict__ cnt64,
                                                     const int* __restrict__ bpre,
                                                     int* __restrict__ rowstart) {
    __shared__ int s[1024];
    const int t = threadIdx.x;
    int idx = blockIdx.x * 1024 + t;
    int v = (idx < NN) ? (int)cnt64[idx].y : 0;
    s[t] = v;
    __syncthreads();
#pragma unroll
    for (int off = 1; off < 1024; off <<= 1) {
        int u = (t >= off) ? s[t - off] : 0;
        __syncthreads();
        s[t] += u;
        __syncthreads();
    }
    if (idx < NN) rowstart[idx] = s[t] - v + bpre[blockIdx.x];
    if (idx == 0) rowstart[NN] = EE;
}

// atomic-free scatter: 4-byte records (src:16 | w:bf16)
__global__ void fill_kernel(const int* __restrict__ ei, const float* __restrict__ ew,
                            const float* __restrict__ dinv, const int* __restrict__ rowstart,
                            const unsigned* __restrict__ rank, unsigned* __restrict__ eprec4) {
    int e = blockIdx.x * blockDim.x + threadIdx.x;
    if (e >= EE) return;
    int s = ei[e], d = ei[EE + e];
    int idx = rowstart[d] + (int)rank[e];
    float w = dinv[s] * ew[e] * dinv[d];
    eprec4[idx] = ((unsigned)s << 16) | (unsigned)f2b(w);
}

// ---------------- x fp32 -> bf16 ----------------

__global__ void xconv_kernel(const float4* __restrict__ x, uint2* __restrict__ xb, int n4) {
    int i = blockIdx.x * 256 + threadIdx.x;
    if (i < n4) {
        float4 v = x[i];
        xb[i] = make_uint2(pack2(v.x, v.y), pack2(v.z, v.w));
    }
}

// ---------------- weight convert: Wt[n][k] bf16, combined [Wg | Ws], pad rows = 0

__global__ void wconv_kernel(const float* __restrict__ Wg, const float* __restrict__ Ws,
                             unsigned short* __restrict__ Wt, int K, int Fo, int N2) {
    int idx = blockIdx.x * 256 + threadIdx.x;
    if (idx >= N2 * K) return;
    int n = idx / K, k = idx - n * K;
    float v = 0.f;
    if (n < Fo) v = Wg[(size_t)k * Fo + n];
    else if (n < 2 * Fo) v = Ws[(size_t)k * Fo + (n - Fo)];
    Wt[idx] = f2b(v);
}

// ---------------- MFMA dual GEMM, async LDS staging (R9-verified) ----------------

__global__ __launch_bounds__(256) void gemm_mfma(const unsigned short* __restrict__ Ab,
                                                 const unsigned short* __restrict__ Wt,
                                                 const float* __restrict__ bias,
                                                 unsigned short* __restrict__ Cg,
                                                 unsigned short* __restrict__ Cs,
                                                 int M, int K, int Fo) {
    __shared__ unsigned short sA[128 * 64];
    __shared__ unsigned short sB[128 * 64];

    const int t = threadIdx.x;
    const int lane = t & 63;
    const int wave = t >> 6;
    const int wm = wave >> 1, wn = wave & 1;
    const int l15 = lane & 15, quad = lane >> 4;
    const int row0 = blockIdx.x * 128;
    const int colbase = blockIdx.y * 128;

    fx4 acc[4][4];
#pragma unroll
    for (int r = 0; r < 4; ++r)
#pragma unroll
        for (int c = 0; c < 4; ++c) acc[r][c] = (fx4){0.f, 0.f, 0.f, 0.f};

    for (int kc = 0; kc < K; kc += 64) {
#pragma unroll
        for (int j = 0; j < 4; ++j) {
            int c = wave * 4 + j;              // chunk 0..15
            int rb = c >> 1, kh = c & 1;
            int ar = row0 + rb * 16 + l15;
            if (ar >= M) ar = M - 1;           // clamp: dup loads, C rows >= M unwritten
            int ak = kc + kh * 32 + quad * 8;
            gload_lds16(Ab + (size_t)ar * K + ak, sA + c * 512);
            int br = colbase + rb * 16 + l15;  // always < N2 (Wt padded)
            gload_lds16(Wt + (size_t)br * K + ak, sB + c * 512);
        }
        __syncthreads();

#pragma unroll
        for (int kh = 0; kh < 2; ++kh) {
            short8 a[4], b[4];
#pragma unroll
            for (int r = 0; r < 4; ++r)
                a[r] = *reinterpret_cast<const short8*>(&sA[((wm * 4 + r) * 2 + kh) * 512 + lane * 8]);
#pragma unroll
            for (int c = 0; c < 4; ++c)
                b[c] = *reinterpret_cast<const short8*>(&sB[((wn * 4 + c) * 2 + kh) * 512 + lane * 8]);
#pragma unroll
            for (int r = 0; r < 4; ++r)
#pragma unroll
                for (int c = 0; c < 4; ++c)
                    acc[r][c] = __builtin_amdgcn_mfma_f32_16x16x32_bf16(a[r], b[c], acc[r][c], 0, 0, 0);
        }
        __syncthreads();
    }

    // epilogue (C/D layout: col = lane&15, row = quad*4 + reg)
#pragma unroll
    for (int c = 0; c < 4; ++c) {
        int f = colbase + wn * 64 + c * 16 + l15;
        if (f >= 2 * Fo) continue;
        bool isG = (f < Fo);
        int col = isG ? f : f - Fo;
        float badd = isG ? 0.f : bias[col];
        unsigned short* base = isG ? Cg : Cs;
#pragma unroll
        for (int r = 0; r < 4; ++r) {
#pragma unroll
            for (int reg = 0; reg < 4; ++reg) {
                int row = row0 + wm * 64 + r * 16 + quad * 4 + reg;
                if (row < M) base[(size_t)row * Fo + col] = f2b(acc[r][c][reg] + badd);
            }
        }
    }
}

// ---------------- pull aggregation + fused BN/ReLU, Fo=128, bf16 in/out
// 4-byte edge records: src = rec>>16, w = bf16(rec&0xffff)

template <bool RELU>
__global__ __launch_bounds__(256) void agg128_kernel(
    const int* __restrict__ rowstart, const unsigned* __restrict__ eprec4,
    const unsigned* __restrict__ hw, const unsigned* __restrict__ selfC,
    const float* __restrict__ g, const float* __restrict__ be,
    const float* __restrict__ mu, const float* __restrict__ va,
    unsigned* __restrict__ out) {
    int wave = threadIdx.x >> 6;
    int lane = threadIdx.x & 63;
    int n = blockIdx.x * 4 + wave;
    if (n >= NN) return;
    unsigned scp = selfC[n * 64 + lane];
    float acc0 = blo(scp), acc1 = bhi(scp);
    int beg = rowstart[n], end = rowstart[n + 1];
    int i = beg;
    for (; i + 4 <= end; i += 4) {
        unsigned e0 = eprec4[i], e1 = eprec4[i + 1], e2 = eprec4[i + 2], e3 = eprec4[i + 3];
        unsigned v0 = hw[(e0 >> 16) * 64u + lane];
        unsigned v1 = hw[(e1 >> 16) * 64u + lane];
        unsigned v2 = hw[(e2 >> 16) * 64u + lane];
        unsigned v3 = hw[(e3 >> 16) * 64u + lane];
        float w0 = blo(e0), w1 = blo(e1), w2 = blo(e2), w3 = blo(e3);
        acc0 += blo(v0) * w0; acc1 += bhi(v0) * w0;
        acc0 += blo(v1) * w1; acc1 += bhi(v1) * w1;
        acc0 += blo(v2) * w2; acc1 += bhi(v2) * w2;
        acc0 += blo(v3) * w3; acc1 += bhi(v3) * w3;
    }
    for (; i < end; ++i) {
        unsigned e = eprec4[i];
        unsigned v = hw[(e >> 16) * 64u + lane];
        float w = blo(e);
        acc0 += blo(v) * w; acc1 += bhi(v) * w;
    }
    float2 m2 = reinterpret_cast<const float2*>(mu)[lane];
    float2 v2f = reinterpret_cast<const float2*>(va)[lane];
    float2 g2 = reinterpret_cast<const float2*>(g)[lane];
    float2 b2 = reinterpret_cast<const float2*>(be)[lane];
    float r0 = (acc0 - m2.x) * rsqrtf(v2f.x + EPSV) * g2.x + b2.x;
    float r1 = (acc1 - m2.y) * rsqrtf(v2f.y + EPSV) * g2.y + b2.y;
    if (RELU) {
        r0 = fmaxf(r0, 0.f);
        r1 = fmaxf(r1, 0.f);
    }
    out[n * 64 + lane] = pack2(r0, r1);
}

// ---------------- final layer aggregation, Fo=40, fp32 out

__global__ __launch_bounds__(256) void agg40_kernel(
    const int* __restrict__ rowstart, const unsigned* __restrict__ eprec4,
    const unsigned* __restrict__ hw, const unsigned* __restrict__ selfC,
    const float* __restrict__ g, const float* __restrict__ be,
    const float* __restrict__ mu, const float* __restrict__ va,
    float* __restrict__ out) {
    int wave = threadIdx.x >> 6;
    int lane = threadIdx.x & 63;
    int n = blockIdx.x * 4 + wave;
    if (n >= NN) return;
    int grp = lane / 20;
    int fl = lane - grp * 20;
    float acc0 = 0.f, acc1 = 0.f;
    int beg = rowstart[n], end = rowstart[n + 1];
    if (grp < 3) {
        for (int i = beg + grp; i < end; i += 3) {
            unsigned e = eprec4[i];
            unsigned v = hw[(e >> 16) * 20u + fl];
            float w = blo(e);
            acc0 += blo(v) * w;
            acc1 += bhi(v) * w;
        }
    }
    acc0 += __shfl(acc0, lane + 20) + __shfl(acc0, lane + 40);
    acc1 += __shfl(acc1, lane + 20) + __shfl(acc1, lane + 40);
    if (lane < 20) {
        int f0 = lane * 2;
        unsigned scp = selfC[n * 20 + lane];
        acc0 += blo(scp);
        acc1 += bhi(scp);
        float2 m2 = reinterpret_cast<const float2*>(mu)[lane];
        float2 v2f = reinterpret_cast<const float2*>(va)[lane];
        float2 g2 = reinterpret_cast<const float2*>(g)[lane];
        float2 b2 = reinterpret_cast<const float2*>(be)[lane];
        float r0 = (acc0 - m2.x) * rsqrtf(v2f.x + EPSV) * g2.x + b2.x;
        float r1 = (acc1 - m2.y) * rsqrtf(v2f.y + EPSV) * g2.y + b2.y;
        *reinterpret_cast<float2*>(&out[(size_t)n * 40 + f0]) = make_float2(r0, r1);
    }
}

// ---------------- launch ----------------

extern "C" void kernel_launch(void* const* d_in, const int* in_sizes, int n_in,
                              void* d_out, int out_size, void* d_ws, size_t ws_size,
                              hipStream_t stream) {
    const float* x = (const float*)d_in[0];
    const int* ei = (const int*)d_in[1];
    const float* ew = (const float*)d_in[2];

    const float* wg[3]  = {(const float*)d_in[3],  (const float*)d_in[10], (const float*)d_in[17]};
    const float* wsf[3] = {(const float*)d_in[4],  (const float*)d_in[11], (const float*)d_in[18]};
    const float* bs[3]  = {(const float*)d_in[5],  (const float*)d_in[12], (const float*)d_in[19]};
    const float* gm[3]  = {(const float*)d_in[6],  (const float*)d_in[13], (const float*)d_in[20]};
    const float* bt[3]  = {(const float*)d_in[7],  (const float*)d_in[14], (const float*)d_in[21]};
    const float* mu[3]  = {(const float*)d_in[8],  (const float*)d_in[15], (const float*)d_in[22]};
    const float* vr[3]  = {(const float*)d_in[9],  (const float*)d_in[16], (const float*)d_in[23]};

    // workspace layout (float-sized slots), total ~60.2 MB, regions disjoint
    // (except bufH aliasing xb intentionally: xb dead after gemm1)
    float* W = (float*)d_ws;
    unsigned long long* cnt64 = (unsigned long long*)W;       // [0, 100096)
    float* dinv     = W + 100096;                 // [100096, 150144)
    unsigned* rank  = (unsigned*)(W + 150144);    // [150144, 1150144)
    int*   bsum     = (int*)(W + 1150144);        // [1150144, 1150208)
    int*   bpre     = (int*)(W + 1150208);        // [1150208, 1150272)
    int*   rowstart = (int*)(W + 1150272);        // [1150272, 1200384)
    unsigned* eprec4 = (unsigned*)(W + 1200384);  // [1200384, 2200384)
    unsigned short* Wt1 = (unsigned short*)(W + 2200384);     // [2200384, 2233152)
    unsigned short* Wt2 = (unsigned short*)(W + 2233152);     // [2233152, 2249536)
    unsigned short* Wt3 = (unsigned short*)(W + 2249536);     // [2249536, 2257728)
    unsigned short* xb  = (unsigned short*)(W + 2257728);     // [2257728, 8657728)
    unsigned short* bufH = (unsigned short*)(W + 2257728);    // aliases xb
    unsigned short* bufHW = (unsigned short*)(W + 8657728);   // [8657728, 11857728)
    unsigned short* bufSb = (unsigned short*)(W + 11857728);  // [11857728, 15057728)

    const int B = 256;
    const int SB = 49;

    // preprocessing: degree norm + dst-sorted CSR (atomic-free fill)
    zero_kernel<<<(100096 + B - 1) / B, B, 0, stream>>>(W, 100096);  // cnt64 only
    cntdeg_kernel<<<(EE + B - 1) / B, B, 0, stream>>>(ei, ew, cnt64, rank);
    dinvsum_kernel<<<SB, 1024, 0, stream>>>((const uint2*)cnt64, dinv, bsum);
    scanB_kernel<<<1, 64, 0, stream>>>(bsum, bpre, SB);
    scanC_kernel<<<SB, 1024, 0, stream>>>((const uint2*)cnt64, bpre, rowstart);
    fill_kernel<<<(EE + B - 1) / B, B, 0, stream>>>(ei, ew, dinv, rowstart, rank, eprec4);

    // conversions
    xconv_kernel<<<(NN * 64 + B - 1) / B, B, 0, stream>>>((const float4*)x, (uint2*)xb, NN * 64);
    wconv_kernel<<<(256 * 256 + B - 1) / B, B, 0, stream>>>(wg[0], wsf[0], Wt1, 256, 128, 256);
    wconv_kernel<<<(256 * 128 + B - 1) / B, B, 0, stream>>>(wg[1], wsf[1], Wt2, 128, 128, 256);
    wconv_kernel<<<(128 * 128 + B - 1) / B, B, 0, stream>>>(wg[2], wsf[2], Wt3, 128, 40, 128);

    const int aggGrid = (NN + 3) / 4;
    dim3 g2((NN + 127) / 128, 2), g1((NN + 127) / 128, 1);

    // layer 1: xb bf16 [N,256] -> 128
    gemm_mfma<<<g2, B, 0, stream>>>(xb, Wt1, bs[0], bufHW, bufSb, NN, 256, 128);
    agg128_kernel<true><<<aggGrid, B, 0, stream>>>(rowstart, eprec4, (const unsigned*)bufHW,
                                                   (const unsigned*)bufSb, gm[0], bt[0], mu[0], vr[0],
                                                   (unsigned*)bufH);

    // layer 2: h bf16 [N,128] -> 128
    gemm_mfma<<<g2, B, 0, stream>>>(bufH, Wt2, bs[1], bufHW, bufSb, NN, 128, 128);
    agg128_kernel<true><<<aggGrid, B, 0, stream>>>(rowstart, eprec4, (const unsigned*)bufHW,
                                                   (const unsigned*)bufSb, gm[1], bt[1], mu[1], vr[1],
                                                   (unsigned*)bufH);

    // layer 3: h bf16 [N,128] -> 40 (cols padded to 128), fp32 out
    gemm_mfma<<<g1, B, 0, stream>>>(bufH, Wt3, bs[2], bufHW, bufSb, NN, 128, 40);
    agg40_kernel<<<aggGrid, B, 0, stream>>>(rowstart, eprec4, (const unsigned*)bufHW,
                                            (const unsigned*)bufSb, gm[2], bt[2], mu[2], vr[2],
                                            (float*)d_out);
}

// Round 12
// 428.112 us; speedup vs baseline: 10.7486x; 1.0102x over previous
//
#include <hip/hip_runtime.h>
#include <hip/hip_bf16.h>

#define NN 50000
#define EE 1000000
static constexpr float EPSV = 1e-3f;
static constexpr float FIXSCALE = 16777216.f;  // 2^24

typedef __attribute__((ext_vector_type(8))) short short8;
typedef __attribute__((ext_vector_type(4))) float fx4;

__device__ inline float blo(unsigned u) { return __uint_as_float(u << 16); }
__device__ inline float bhi(unsigned u) { return __uint_as_float(u & 0xffff0000u); }
__device__ inline unsigned short f2b(float f) {
    __hip_bfloat16 h = __float2bfloat16(f);
    return *(unsigned short*)&h;
}
__device__ inline unsigned pack2(float a, float b) {
    return (unsigned)f2b(a) | ((unsigned)f2b(b) << 16);
}

// async global->LDS DMA, 16 B per lane
__device__ inline void gload_lds16(const unsigned short* g, unsigned short* ldsbase) {
    __builtin_amdgcn_global_load_lds(
        (const __attribute__((address_space(1))) unsigned int*)(const void*)g,
        (__attribute__((address_space(3))) unsigned int*)(void*)ldsbase, 16, 0, 0);
}

// ---------------- preprocessing ----------------

__global__ void zero_kernel(float* p, int n) {
    int i = blockIdx.x * blockDim.x + threadIdx.x;
    if (i < n) p[i] = 0.f;
}

// Fused: [0,CB) cntdeg atomics | [CB,CB+XB) xconv | then wconv1/2/3.
// Atomic blocks first (latency-bound long pole); BW-bound conversion blocks
// co-schedule into the idle VALU/BW (m114 overlap).
#define CB 3907    // ceil(EE/256)
#define XB 12500   // NN*64 uint2 / 256
#define WB1 256    // 256*256/256
#define WB2 128
#define WB3 64

__global__ void pre_kernel(const int* __restrict__ ei, const float* __restrict__ ew,
                           unsigned long long* __restrict__ cnt64, unsigned* __restrict__ rank,
                           const float4* __restrict__ x, uint2* __restrict__ xb,
                           const float* __restrict__ wg1, const float* __restrict__ ws1,
                           unsigned short* __restrict__ Wt1,
                           const float* __restrict__ wg2, const float* __restrict__ ws2,
                           unsigned short* __restrict__ Wt2,
                           const float* __restrict__ wg3, const float* __restrict__ ws3,
                           unsigned short* __restrict__ Wt3) {
    int b = blockIdx.x;
    int t = threadIdx.x;
    if (b < CB) {
        int e = b * 256 + t;
        if (e < EE) {
            int d = ei[EE + e];
            unsigned fx = __float2uint_rn(ew[e] * FIXSCALE);
            unsigned long long old =
                atomicAdd(&cnt64[d], 0x100000000ull | (unsigned long long)fx);
            rank[e] = (unsigned)(old >> 32);
        }
    } else if (b < CB + XB) {
        int i = (b - CB) * 256 + t;  // i < NN*64 always
        float4 v = x[i];
        xb[i] = make_uint2(pack2(v.x, v.y), pack2(v.z, v.w));
    } else if (b < CB + XB + WB1) {
        int idx = (b - CB - XB) * 256 + t;  // [0, 65536)
        int n = idx >> 8, k = idx & 255;    // K=256, Fo=128, N2=256
        float v = (n < 128) ? wg1[(size_t)k * 128 + n]
                            : ws1[(size_t)k * 128 + (n - 128)];
        Wt1[idx] = f2b(v);
    } else if (b < CB + XB + WB1 + WB2) {
        int idx = (b - CB - XB - WB1) * 256 + t;  // [0, 32768)
        int n = idx >> 7, k = idx & 127;          // K=128, Fo=128, N2=256
        float v = (n < 128) ? wg2[(size_t)k * 128 + n]
                            : ws2[(size_t)k * 128 + (n - 128)];
        Wt2[idx] = f2b(v);
    } else {
        int idx = (b - CB - XB - WB1 - WB2) * 256 + t;  // [0, 16384)
        int n = idx >> 7, k = idx & 127;                // K=128, Fo=40, N2=128
        float v = 0.f;
        if (n < 40) v = wg3[(size_t)k * 40 + n];
        else if (n < 80) v = ws3[(size_t)k * 40 + (n - 40)];
        Wt3[idx] = f2b(v);
    }
}

__global__ __launch_bounds__(1024) void dinvsum_kernel(const uint2* __restrict__ cnt64,
                                                       float* __restrict__ dinv,
                                                       int* __restrict__ bsum) {
    __shared__ int s[1024];
    const int t = threadIdx.x;
    int idx = blockIdx.x * 1024 + t;
    uint2 cv = make_uint2(0u, 0u);
    if (idx < NN) cv = cnt64[idx];
    float deg = (float)cv.x * (1.f / FIXSCALE);
    if (idx < NN) dinv[idx] = (deg > 0.f) ? rsqrtf(deg) : 0.f;
    s[t] = (int)cv.y;
    __syncthreads();
#pragma unroll
    for (int off = 512; off > 0; off >>= 1) {
        if (t < off) s[t] += s[t + off];
        __syncthreads();
    }
    if (t == 0) bsum[blockIdx.x] = s[0];
}

__global__ __launch_bounds__(64) void scanB_kernel(const int* __restrict__ bsum,
                                                   int* __restrict__ bpre, int nb) {
    int t = threadIdx.x;
    int v = (t < nb) ? bsum[t] : 0;
    int own = v;
#pragma unroll
    for (int off = 1; off < 64; off <<= 1) {
        int u = __shfl_up(v, off);
        if (t >= off) v += u;
    }
    if (t < nb) bpre[t] = v - own;
}

__global__ __launch_bounds__(1024) void scanC_kernel(const uint2* __restrict__ cnt64,
                                                     const int* __restrict__ bpre,
                                                     int* __restrict__ rowstart) {
    __shared__ int s[1024];
    const int t = threadIdx.x;
    int idx = blockIdx.x * 1024 + t;
    int v = (idx < NN) ? (int)cnt64[idx].y : 0;
    s[t] = v;
    __syncthreads();
#pragma unroll
    for (int off = 1; off < 1024; off <<= 1) {
        int u = (t >= off) ? s[t - off] : 0;
        __syncthreads();
        s[t] += u;
        __syncthreads();
    }
    if (idx < NN) rowstart[idx] = s[t] - v + bpre[blockIdx.x];
    if (idx == 0) rowstart[NN] = EE;
}

// atomic-free scatter: 4-byte records (src:16 | w:bf16)
__global__ void fill_kernel(const int* __restrict__ ei, const float* __restrict__ ew,
                            const float* __restrict__ dinv, const int* __restrict__ rowstart,
                            const unsigned* __restrict__ rank, unsigned* __restrict__ eprec4) {
    int e = blockIdx.x * blockDim.x + threadIdx.x;
    if (e >= EE) return;
    int s = ei[e], d = ei[EE + e];
    int idx = rowstart[d] + (int)rank[e];
    float w = dinv[s] * ew[e] * dinv[d];
    eprec4[idx] = ((unsigned)s << 16) | (unsigned)f2b(w);
}

// ---------------- MFMA dual GEMM, async LDS staging (R9-verified) ----------------

__global__ __launch_bounds__(256) void gemm_mfma(const unsigned short* __restrict__ Ab,
                                                 const unsigned short* __restrict__ Wt,
                                                 const float* __restrict__ bias,
                                                 unsigned short* __restrict__ Cg,
                                                 unsigned short* __restrict__ Cs,
                                                 int M, int K, int Fo) {
    __shared__ unsigned short sA[128 * 64];
    __shared__ unsigned short sB[128 * 64];

    const int t = threadIdx.x;
    const int lane = t & 63;
    const int wave = t >> 6;
    const int wm = wave >> 1, wn = wave & 1;
    const int l15 = lane & 15, quad = lane >> 4;
    const int row0 = blockIdx.x * 128;
    const int colbase = blockIdx.y * 128;

    fx4 acc[4][4];
#pragma unroll
    for (int r = 0; r < 4; ++r)
#pragma unroll
        for (int c = 0; c < 4; ++c) acc[r][c] = (fx4){0.f, 0.f, 0.f, 0.f};

    for (int kc = 0; kc < K; kc += 64) {
#pragma unroll
        for (int j = 0; j < 4; ++j) {
            int c = wave * 4 + j;
            int rb = c >> 1, kh = c & 1;
            int ar = row0 + rb * 16 + l15;
            if (ar >= M) ar = M - 1;
            int ak = kc + kh * 32 + quad * 8;
            gload_lds16(Ab + (size_t)ar * K + ak, sA + c * 512);
            int br = colbase + rb * 16 + l15;
            gload_lds16(Wt + (size_t)br * K + ak, sB + c * 512);
        }
        __syncthreads();

#pragma unroll
        for (int kh = 0; kh < 2; ++kh) {
            short8 a[4], b[4];
#pragma unroll
            for (int r = 0; r < 4; ++r)
                a[r] = *reinterpret_cast<const short8*>(&sA[((wm * 4 + r) * 2 + kh) * 512 + lane * 8]);
#pragma unroll
            for (int c = 0; c < 4; ++c)
                b[c] = *reinterpret_cast<const short8*>(&sB[((wn * 4 + c) * 2 + kh) * 512 + lane * 8]);
#pragma unroll
            for (int r = 0; r < 4; ++r)
#pragma unroll
                for (int c = 0; c < 4; ++c)
                    acc[r][c] = __builtin_amdgcn_mfma_f32_16x16x32_bf16(a[r], b[c], acc[r][c], 0, 0, 0);
        }
        __syncthreads();
    }

#pragma unroll
    for (int c = 0; c < 4; ++c) {
        int f = colbase + wn * 64 + c * 16 + l15;
        if (f >= 2 * Fo) continue;
        bool isG = (f < Fo);
        int col = isG ? f : f - Fo;
        float badd = isG ? 0.f : bias[col];
        unsigned short* base = isG ? Cg : Cs;
#pragma unroll
        for (int r = 0; r < 4; ++r) {
#pragma unroll
            for (int reg = 0; reg < 4; ++reg) {
                int row = row0 + wm * 64 + r * 16 + quad * 4 + reg;
                if (row < M) base[(size_t)row * Fo + col] = f2b(acc[r][c][reg] + badd);
            }
        }
    }
}

// ---------------- pull aggregation + fused BN/ReLU, Fo=128 (R10-proven) ----------------

template <bool RELU>
__global__ __launch_bounds__(256) void agg128_kernel(
    const int* __restrict__ rowstart, const unsigned* __restrict__ eprec4,
    const unsigned* __restrict__ hw, const unsigned* __restrict__ selfC,
    const float* __restrict__ g, const float* __restrict__ be,
    const float* __restrict__ mu, const float* __restrict__ va,
    unsigned* __restrict__ out) {
    int wave = threadIdx.x >> 6;
    int lane = threadIdx.x & 63;
    int n = blockIdx.x * 4 + wave;
    if (n >= NN) return;
    unsigned scp = selfC[n * 64 + lane];
    float acc0 = blo(scp), acc1 = bhi(scp);
    int beg = rowstart[n], end = rowstart[n + 1];
    int i = beg;
    for (; i + 4 <= end; i += 4) {
        unsigned e0 = eprec4[i], e1 = eprec4[i + 1], e2 = eprec4[i + 2], e3 = eprec4[i + 3];
        unsigned v0 = hw[(e0 >> 16) * 64u + lane];
        unsigned v1 = hw[(e1 >> 16) * 64u + lane];
        unsigned v2 = hw[(e2 >> 16) * 64u + lane];
        unsigned v3 = hw[(e3 >> 16) * 64u + lane];
        float w0 = blo(e0), w1 = blo(e1), w2 = blo(e2), w3 = blo(e3);
        acc0 += blo(v0) * w0; acc1 += bhi(v0) * w0;
        acc0 += blo(v1) * w1; acc1 += bhi(v1) * w1;
        acc0 += blo(v2) * w2; acc1 += bhi(v2) * w2;
        acc0 += blo(v3) * w3; acc1 += bhi(v3) * w3;
    }
    for (; i < end; ++i) {
        unsigned e = eprec4[i];
        unsigned v = hw[(e >> 16) * 64u + lane];
        float w = blo(e);
        acc0 += blo(v) * w; acc1 += bhi(v) * w;
    }
    float2 m2 = reinterpret_cast<const float2*>(mu)[lane];
    float2 v2f = reinterpret_cast<const float2*>(va)[lane];
    float2 g2 = reinterpret_cast<const float2*>(g)[lane];
    float2 b2 = reinterpret_cast<const float2*>(be)[lane];
    float r0 = (acc0 - m2.x) * rsqrtf(v2f.x + EPSV) * g2.x + b2.x;
    float r1 = (acc1 - m2.y) * rsqrtf(v2f.y + EPSV) * g2.y + b2.y;
    if (RELU) {
        r0 = fmaxf(r0, 0.f);
        r1 = fmaxf(r1, 0.f);
    }
    out[n * 64 + lane] = pack2(r0, r1);
}

// ---------------- final layer aggregation, Fo=40, fp32 out (R10-proven) ----------------

__global__ __launch_bounds__(256) void agg40_kernel(
    const int* __restrict__ rowstart, const unsigned* __restrict__ eprec4,
    const unsigned* __restrict__ hw, const unsigned* __restrict__ selfC,
    const float* __restrict__ g, const float* __restrict__ be,
    const float* __restrict__ mu, const float* __restrict__ va,
    float* __restrict__ out) {
    int wave = threadIdx.x >> 6;
    int lane = threadIdx.x & 63;
    int n = blockIdx.x * 4 + wave;
    if (n >= NN) return;
    int grp = lane / 20;
    int fl = lane - grp * 20;
    float acc0 = 0.f, acc1 = 0.f;
    int beg = rowstart[n], end = rowstart[n + 1];
    if (grp < 3) {
        for (int i = beg + grp; i < end; i += 3) {
            unsigned e = eprec4[i];
            unsigned v = hw[(e >> 16) * 20u + fl];
            float w = blo(e);
            acc0 += blo(v) * w;
            acc1 += bhi(v) * w;
        }
    }
    acc0 += __shfl(acc0, lane + 20) + __shfl(acc0, lane + 40);
    acc1 += __shfl(acc1, lane + 20) + __shfl(acc1, lane + 40);
    if (lane < 20) {
        int f0 = lane * 2;
        unsigned scp = selfC[n * 20 + lane];
        acc0 += blo(scp);
        acc1 += bhi(scp);
        float2 m2 = reinterpret_cast<const float2*>(mu)[lane];
        float2 v2f = reinterpret_cast<const float2*>(va)[lane];
        float2 g2 = reinterpret_cast<const float2*>(g)[lane];
        float2 b2 = reinterpret_cast<const float2*>(be)[lane];
        float r0 = (acc0 - m2.x) * rsqrtf(v2f.x + EPSV) * g2.x + b2.x;
        float r1 = (acc1 - m2.y) * rsqrtf(v2f.y + EPSV) * g2.y + b2.y;
        *reinterpret_cast<float2*>(&out[(size_t)n * 40 + f0]) = make_float2(r0, r1);
    }
}

// ---------------- launch ----------------

extern "C" void kernel_launch(void* const* d_in, const int* in_sizes, int n_in,
                              void* d_out, int out_size, void* d_ws, size_t ws_size,
                              hipStream_t stream) {
    const float* x = (const float*)d_in[0];
    const int* ei = (const int*)d_in[1];
    const float* ew = (const float*)d_in[2];

    const float* wg[3]  = {(const float*)d_in[3],  (const float*)d_in[10], (const float*)d_in[17]};
    const float* wsf[3] = {(const float*)d_in[4],  (const float*)d_in[11], (const float*)d_in[18]};
    const float* bs[3]  = {(const float*)d_in[5],  (const float*)d_in[12], (const float*)d_in[19]};
    const float* gm[3]  = {(const float*)d_in[6],  (const float*)d_in[13], (const float*)d_in[20]};
    const float* bt[3]  = {(const float*)d_in[7],  (const float*)d_in[14], (const float*)d_in[21]};
    const float* mu[3]  = {(const float*)d_in[8],  (const float*)d_in[15], (const float*)d_in[22]};
    const float* vr[3]  = {(const float*)d_in[9],  (const float*)d_in[16], (const float*)d_in[23]};

    // workspace layout (float-sized slots), regions disjoint
    // (except bufH aliasing xb intentionally: xb dead after gemm1)
    float* W = (float*)d_ws;
    unsigned long long* cnt64 = (unsigned long long*)W;       // [0, 100096)
    float* dinv     = W + 100096;                 // [100096, 150144)
    unsigned* rank  = (unsigned*)(W + 150144);    // [150144, 1150144)
    int*   bsum     = (int*)(W + 1150144);        // [1150144, 1150208)
    int*   bpre     = (int*)(W + 1150208);        // [1150208, 1150272)
    int*   rowstart = (int*)(W + 1150272);        // [1150272, 1200384)
    unsigned* eprec4 = (unsigned*)(W + 1200384);  // [1200384, 2200384)
    unsigned short* Wt1 = (unsigned short*)(W + 2200384);     // [2200384, 2233152)
    unsigned short* Wt2 = (unsigned short*)(W + 2233152);     // [2233152, 2249536)
    unsigned short* Wt3 = (unsigned short*)(W + 2249536);     // [2249536, 2257728)
    unsigned short* xb  = (unsigned short*)(W + 2257728);     // [2257728, 8657728)
    unsigned short* bufH = (unsigned short*)(W + 2257728);    // aliases xb
    unsigned short* bufHW = (unsigned short*)(W + 8657728);   // [8657728, 11857728)
    unsigned short* bufSb = (unsigned short*)(W + 11857728);  // [11857728, 15057728)

    const int B = 256;
    const int SB = 49;

    // preprocessing: zero, then fused atomics+conversions, then CSR build
    zero_kernel<<<(100096 + B - 1) / B, B, 0, stream>>>(W, 100096);  // cnt64
    pre_kernel<<<CB + XB + WB1 + WB2 + WB3, B, 0, stream>>>(
        ei, ew, cnt64, rank, (const float4*)x, (uint2*)xb,
        wg[0], wsf[0], Wt1, wg[1], wsf[1], Wt2, wg[2], wsf[2], Wt3);
    dinvsum_kernel<<<SB, 1024, 0, stream>>>((const uint2*)cnt64, dinv, bsum);
    scanB_kernel<<<1, 64, 0, stream>>>(bsum, bpre, SB);
    scanC_kernel<<<SB, 1024, 0, stream>>>((const uint2*)cnt64, bpre, rowstart);
    fill_kernel<<<(EE + B - 1) / B, B, 0, stream>>>(ei, ew, dinv, rowstart, rank, eprec4);

    const int aggGrid = (NN + 3) / 4;
    dim3 g2((NN + 127) / 128, 2), g1((NN + 127) / 128, 1);

    // layer 1: xb bf16 [N,256] -> 128
    gemm_mfma<<<g2, B, 0, stream>>>(xb, Wt1, bs[0], bufHW, bufSb, NN, 256, 128);
    agg128_kernel<true><<<aggGrid, B, 0, stream>>>(rowstart, eprec4, (const unsigned*)bufHW,
                                                   (const unsigned*)bufSb, gm[0], bt[0], mu[0], vr[0],
                                                   (unsigned*)bufH);

    // layer 2: h bf16 [N,128] -> 128
    gemm_mfma<<<g2, B, 0, stream>>>(bufH, Wt2, bs[1], bufHW, bufSb, NN, 128, 128);
    agg128_kernel<true><<<aggGrid, B, 0, stream>>>(rowstart, eprec4, (const unsigned*)bufHW,
                                                   (const unsigned*)bufSb, gm[1], bt[1], mu[1], vr[1],
                                                   (unsigned*)bufH);

    // layer 3: h bf16 [N,128] -> 40 (cols padded to 128), fp32 out
    gemm_mfma<<<g1, B, 0, stream>>>(bufH, Wt3, bs[2], bufHW, bufSb, NN, 128, 40);
    agg40_kernel<<<aggGrid, B, 0, stream>>>(rowstart, eprec4, (const unsigned*)bufHW,
                                            (const unsigned*)bufSb, gm[2], bt[2], mu[2], vr[2],
                                            (float*)d_out);
}